// Round 2
// baseline (5354.809 us; speedup 1.0000x reference)
//
#include <hip/hip_runtime.h>
#include <math.h>

#define TT 12
#define NN 20000
#define EE 320000
#define NPW 4

__device__ __forceinline__ float dot4(float4 a, float4 b) {
    return a.x * b.x + a.y * b.y + a.z * b.z + a.w * b.w;
}

__device__ __forceinline__ float wsum64(float v) {
#pragma unroll
    for (int o = 32; o >= 1; o >>= 1) v += __shfl_xor(v, o);
    return v;
}

// ---------------- weight transpose (once per launch) ----------------
// WT layout (floats): WqT@0, WkT@4096, WvT@8192, WoT@12288,
// CzT@16384, DzT@20480, CrT@24576, DrT@28672, ChT@32768, DhT@36864,
// W1T@40960 (256x64), W2T@57344 (64x256)
__global__ void k_transpose(const float* __restrict__ Wq, const float* __restrict__ Wk,
                            const float* __restrict__ Wv, const float* __restrict__ Wo,
                            const float* __restrict__ Cz, const float* __restrict__ Dz,
                            const float* __restrict__ Cr, const float* __restrict__ Dr,
                            const float* __restrict__ Ch, const float* __restrict__ Dh,
                            const float* __restrict__ W1, const float* __restrict__ W2,
                            float* __restrict__ WT) {
    int tid = blockIdx.x * 256 + threadIdx.x;
    if (tid < 40960) {
        int m = tid >> 12, r = tid & 4095;
        int i = r >> 6, j = r & 63;
        const float* src;
        switch (m) {
            case 0: src = Wq; break; case 1: src = Wk; break;
            case 2: src = Wv; break; case 3: src = Wo; break;
            case 4: src = Cz; break; case 5: src = Dz; break;
            case 6: src = Cr; break; case 7: src = Dr; break;
            case 8: src = Ch; break; default: src = Dh; break;
        }
        WT[m * 4096 + j * 64 + i] = src[i * 64 + j];
    } else if (tid < 40960 + 16384) {
        int r = tid - 40960;
        int i = r >> 8, j = r & 255;            // W1 is (64,256)
        WT[40960 + j * 64 + i] = W1[i * 256 + j];
    } else if (tid < 73728) {
        int r = tid - 57344;
        int k = r >> 6, d = r & 63;             // W2 is (256,64)
        WT[57344 + d * 256 + k] = W2[k * 64 + d];
    }
}

// ---------------- CSR build ----------------
__global__ void k_zero_offs(int* __restrict__ offs) {
    int i = blockIdx.x * 256 + threadIdx.x;
    if (i < NN + 1) offs[i] = 0;
}
__global__ void k_count(const int* __restrict__ dst, int* __restrict__ offs) {
    int e = blockIdx.x * 256 + threadIdx.x;
    if (e < EE) atomicAdd(&offs[dst[e] + 1], 1);
}
__global__ void k_scan(int* __restrict__ offs, int* __restrict__ cur) {
    __shared__ int buf[1024];
    __shared__ int carry;
    int tid = threadIdx.x;
    if (tid == 0) carry = 0;
    __syncthreads();
    const int total = NN + 1;
    for (int base = 0; base < total; base += 1024) {
        int idx = base + tid;
        int v = (idx < total) ? offs[idx] : 0;
        buf[tid] = v;
        __syncthreads();
        for (int o = 1; o < 1024; o <<= 1) {
            int t = (tid >= o) ? buf[tid - o] : 0;
            __syncthreads();
            buf[tid] += t;
            __syncthreads();
        }
        int incl = buf[tid] + carry;
        if (idx < total) offs[idx] = incl;
        __syncthreads();
        if (tid == 1023) carry += buf[1023];
        __syncthreads();
    }
    for (int i = tid; i < NN; i += 1024) cur[i] = offs[i];
}
__global__ void k_fill(const int* __restrict__ src, const int* __restrict__ dst,
                       const float* __restrict__ w, int* __restrict__ cur,
                       int* __restrict__ esrc, float* __restrict__ ews) {
    int e = blockIdx.x * 256 + threadIdx.x;
    if (e < EE) {
        int dn = dst[e];
        int slot = atomicAdd(&cur[dn], 1);
        esrc[slot] = src[e];
        ews[slot] = w[e];
    }
}

// ---------------- fused per-node transformer ----------------
__global__ void k_transformer(const float* __restrict__ x_seq,
                              const float* __restrict__ Wpi, const float* __restrict__ bpi,
                              const float* __restrict__ WqT, const float* __restrict__ bq,
                              const float* __restrict__ WkT, const float* __restrict__ bk,
                              const float* __restrict__ WvT, const float* __restrict__ bv,
                              const float* __restrict__ WoT, const float* __restrict__ bo,
                              const float* __restrict__ g1, const float* __restrict__ be1,
                              const float* __restrict__ W1T, const float* __restrict__ b1,
                              const float* __restrict__ W2T, const float* __restrict__ b2,
                              const float* __restrict__ g2, const float* __restrict__ be2,
                              const float* __restrict__ Wpo, const float* __restrict__ bpo,
                              float* __restrict__ XS) {
    __shared__ __align__(16) float sX[4][TT][68];
    __shared__ __align__(16) float sQ[4][TT][68];
    __shared__ __align__(16) float sK[4][TT][68];
    __shared__ __align__(16) float sV[4][TT][68];
    const int wid = threadIdx.x >> 6;
    const int d = threadIdx.x & 63;
    const int n = blockIdx.x * 4 + wid;

    float xr[TT];
    {
        float wpid = Wpi[d], bpid = bpi[d];
#pragma unroll
        for (int t = 0; t < TT; ++t) {
            float s = x_seq[t * NN + n];
            xr[t] = fmaf(s, wpid, bpid);
            sX[wid][t][d] = xr[t];
        }
    }
    __syncthreads();

    float qa[TT], ka[TT], va[TT];
    {
        float b_q = bq[d], b_k = bk[d], b_v = bv[d];
#pragma unroll
        for (int t = 0; t < TT; ++t) { qa[t] = b_q; ka[t] = b_k; va[t] = b_v; }
    }
    for (int dd0 = 0; dd0 < 64; dd0 += 4) {
        float4 wq = *(const float4*)(WqT + d * 64 + dd0);
        float4 wk = *(const float4*)(WkT + d * 64 + dd0);
        float4 wv = *(const float4*)(WvT + d * 64 + dd0);
#pragma unroll
        for (int t = 0; t < TT; ++t) {
            float4 xv = *(const float4*)(&sX[wid][t][dd0]);
            qa[t] += dot4(xv, wq);
            ka[t] += dot4(xv, wk);
            va[t] += dot4(xv, wv);
        }
    }
#pragma unroll
    for (int t = 0; t < TT; ++t) {
        sQ[wid][t][d] = qa[t];
        sK[wid][t][d] = ka[t];
        sV[wid][t][d] = va[t];
    }
    __syncthreads();

    {
        const int hh = d >> 4;
        const int qi = d & 15;
        if (qi < TT) {
            const float* qr = &sQ[wid][qi][hh * 16];
            float4 q0 = *(const float4*)(qr);
            float4 q1 = *(const float4*)(qr + 4);
            float4 q2 = *(const float4*)(qr + 8);
            float4 q3 = *(const float4*)(qr + 12);
            float attp[TT];
            float mx = -1e30f;
#pragma unroll
            for (int j = 0; j < TT; ++j) {
                const float* kr = &sK[wid][j][hh * 16];
                float s = dot4(q0, *(const float4*)(kr)) +
                          dot4(q1, *(const float4*)(kr + 4)) +
                          dot4(q2, *(const float4*)(kr + 8)) +
                          dot4(q3, *(const float4*)(kr + 12));
                s *= 0.25f;
                attp[j] = s;
                mx = fmaxf(mx, s);
            }
            float ssum = 0.f;
#pragma unroll
            for (int j = 0; j < TT; ++j) { attp[j] = __expf(attp[j] - mx); ssum += attp[j]; }
            float inv = 1.0f / ssum;
            float4 a0 = {0, 0, 0, 0}, a1 = {0, 0, 0, 0}, a2 = {0, 0, 0, 0}, a3 = {0, 0, 0, 0};
#pragma unroll
            for (int j = 0; j < TT; ++j) {
                float p = attp[j] * inv;
                const float* vr = &sV[wid][j][hh * 16];
                float4 v0 = *(const float4*)(vr);
                float4 v1 = *(const float4*)(vr + 4);
                float4 v2 = *(const float4*)(vr + 8);
                float4 v3 = *(const float4*)(vr + 12);
                a0.x += p * v0.x; a0.y += p * v0.y; a0.z += p * v0.z; a0.w += p * v0.w;
                a1.x += p * v1.x; a1.y += p * v1.y; a1.z += p * v1.z; a1.w += p * v1.w;
                a2.x += p * v2.x; a2.y += p * v2.y; a2.z += p * v2.z; a2.w += p * v2.w;
                a3.x += p * v3.x; a3.y += p * v3.y; a3.z += p * v3.z; a3.w += p * v3.w;
            }
            float* ar = &sQ[wid][qi][hh * 16];
            *(float4*)(ar) = a0;
            *(float4*)(ar + 4) = a1;
            *(float4*)(ar + 8) = a2;
            *(float4*)(ar + 12) = a3;
        }
    }
    __syncthreads();

    float x1r[TT];
    {
        float oa[TT];
        float b_o = bo[d];
#pragma unroll
        for (int t = 0; t < TT; ++t) oa[t] = b_o;
        for (int dd0 = 0; dd0 < 64; dd0 += 4) {
            float4 wo = *(const float4*)(WoT + d * 64 + dd0);
#pragma unroll
            for (int t = 0; t < TT; ++t) {
                float4 av = *(const float4*)(&sQ[wid][t][dd0]);
                oa[t] += dot4(av, wo);
            }
        }
        float g1d = g1[d], be1d = be1[d];
        const float inv64 = 1.0f / 64.0f;
#pragma unroll
        for (int t = 0; t < TT; ++t) {
            float y = xr[t] + oa[t];
            float s = wsum64(y);
            float s2 = wsum64(y * y);
            float m = s * inv64;
            float var = s2 * inv64 - m * m;
            x1r[t] = (y - m) * rsqrtf(var + 1e-5f) * g1d + be1d;
        }
    }
#pragma unroll
    for (int t = 0; t < TT; ++t) sX[wid][t][d] = x1r[t];
    __syncthreads();

    float y2[TT];
    {
        float b2d = b2[d];
#pragma unroll
        for (int t = 0; t < TT; ++t) y2[t] = b2d;
    }
    for (int jj = 0; jj < 4; ++jj) {
        int j = jj * 64 + d;
        float hbuf[TT];
        float b1j = b1[j];
#pragma unroll
        for (int t = 0; t < TT; ++t) hbuf[t] = b1j;
        for (int dd0 = 0; dd0 < 64; dd0 += 4) {
            float4 w1 = *(const float4*)(W1T + j * 64 + dd0);
#pragma unroll
            for (int t = 0; t < TT; ++t) {
                float4 xv = *(const float4*)(&sX[wid][t][dd0]);
                hbuf[t] += dot4(xv, w1);
            }
        }
        __syncthreads();
#pragma unroll
        for (int t = 0; t < TT; ++t) sK[wid][t][d] = fmaxf(hbuf[t], 0.0f);
        __syncthreads();
        for (int dd0 = 0; dd0 < 64; dd0 += 4) {
            float4 w2 = *(const float4*)(W2T + d * 256 + jj * 64 + dd0);
#pragma unroll
            for (int t = 0; t < TT; ++t) {
                float4 hv = *(const float4*)(&sK[wid][t][dd0]);
                y2[t] += dot4(hv, w2);
            }
        }
    }

    {
        float g2d = g2[d], be2d = be2[d], wpod = Wpo[d];
        float bpo0 = bpo[0];
        const float inv64 = 1.0f / 64.0f;
#pragma unroll
        for (int t = 0; t < TT; ++t) {
            float y = x1r[t] + y2[t];
            float s = wsum64(y);
            float s2 = wsum64(y * y);
            float m = s * inv64;
            float var = s2 * inv64 - m * m;
            float x2 = (y - m) * rsqrtf(var + 1e-5f) * g2d + be2d;
            float p = wsum64(x2 * wpod);
            if (d == 0) XS[t * NN + n] = p + bpo0;
        }
    }
}

// ---------------- precompute msg_x for ALL timesteps ----------------
// wave per node; lanes split edges; 12 accumulators per lane; wave-reduce.
__global__ void k_gather_x(const float* __restrict__ XS,
                           const int* __restrict__ offs, const int* __restrict__ esrc,
                           const float* __restrict__ ews, float* __restrict__ MX) {
    const int wid = threadIdx.x >> 6;
    const int lane = threadIdx.x & 63;
    const int n = blockIdx.x * 4 + wid;
    int beg = offs[n], end = offs[n + 1];
    float acc[TT];
#pragma unroll
    for (int t = 0; t < TT; ++t) acc[t] = 0.f;
    for (int i = beg + lane; i < end; i += 64) {
        int s = esrc[i];
        float w = ews[i];
#pragma unroll
        for (int t = 0; t < TT; ++t) acc[t] = fmaf(w, XS[t * NN + s], acc[t]);
    }
#pragma unroll
    for (int t = 0; t < TT; ++t) acc[t] = wsum64(acc[t]);
    if (lane == 0) {
#pragma unroll
        for (int t = 0; t < TT; ++t) MX[t * NN + n] = acc[t];
    }
}

// ---------------- GRU step kernel A: z, r gates (4 nodes/wave) ----------------
__global__ void k_gru_a(const float* __restrict__ XS, const float* __restrict__ MX, int tstep,
                        const float* __restrict__ h,
                        const int* __restrict__ offs, const int* __restrict__ esrc,
                        const float* __restrict__ ews,
                        const float* __restrict__ Az, const float* __restrict__ Bz,
                        const float* __restrict__ bz,
                        const float* __restrict__ CzT, const float* __restrict__ DzT,
                        const float* __restrict__ cz,
                        const float* __restrict__ Ar, const float* __restrict__ Br,
                        const float* __restrict__ br,
                        const float* __restrict__ CrT, const float* __restrict__ DrT,
                        const float* __restrict__ cr,
                        float* __restrict__ zb, float* __restrict__ rh) {
    __shared__ __align__(16) float Hs[4][NPW][64];
    __shared__ __align__(16) float Ms[4][NPW][64];
    const int wid = threadIdx.x >> 6;
    const int d = threadIdx.x & 63;
    const int nb = (blockIdx.x * 4 + wid) * NPW;
    const float* xs_t = XS + tstep * NN;
    const float* mx_t = MX + tstep * NN;

    float hreg[NPW], xt[NPW], mxv[NPW];
#pragma unroll
    for (int g = 0; g < NPW; ++g) {
        const int n = nb + g;
        int beg = offs[n], end = offs[n + 1];
        float m0 = 0.f, m1 = 0.f, m2 = 0.f, m3 = 0.f;
        int i = beg;
        for (; i + 3 < end; i += 4) {
            int s0 = __builtin_amdgcn_readfirstlane(esrc[i]);
            int s1 = __builtin_amdgcn_readfirstlane(esrc[i + 1]);
            int s2 = __builtin_amdgcn_readfirstlane(esrc[i + 2]);
            int s3 = __builtin_amdgcn_readfirstlane(esrc[i + 3]);
            float w0 = ews[i], w1 = ews[i + 1], w2 = ews[i + 2], w3 = ews[i + 3];
            m0 = fmaf(w0, h[s0 * 64 + d], m0);
            m1 = fmaf(w1, h[s1 * 64 + d], m1);
            m2 = fmaf(w2, h[s2 * 64 + d], m2);
            m3 = fmaf(w3, h[s3 * 64 + d], m3);
        }
        for (; i < end; ++i) {
            int s = __builtin_amdgcn_readfirstlane(esrc[i]);
            m0 = fmaf(ews[i], h[s * 64 + d], m0);
        }
        float mh = (m0 + m1) + (m2 + m3);
        hreg[g] = h[n * 64 + d];
        xt[g] = xs_t[n];
        mxv[g] = mx_t[n];
        Hs[wid][g][d] = hreg[g];
        Ms[wid][g][d] = mh;
    }
    // LDS is wave-private (indexed by wid): no __syncthreads needed.

    float zacc[NPW], racc[NPW];
    {
        float azd = Az[d], bzd = Bz[d], czd = bz[d] + cz[d];
        float ard = Ar[d], brd = Br[d], crd = br[d] + cr[d];
#pragma unroll
        for (int g = 0; g < NPW; ++g) {
            zacc[g] = fmaf(xt[g], azd, fmaf(mxv[g], bzd, czd));
            racc[g] = fmaf(xt[g], ard, fmaf(mxv[g], brd, crd));
        }
    }
    for (int k0 = 0; k0 < 64; k0 += 4) {
        float4 wcz = *(const float4*)(CzT + d * 64 + k0);
        float4 wdz = *(const float4*)(DzT + d * 64 + k0);
        float4 wcr = *(const float4*)(CrT + d * 64 + k0);
        float4 wdr = *(const float4*)(DrT + d * 64 + k0);
#pragma unroll
        for (int g = 0; g < NPW; ++g) {
            float4 h4 = *(const float4*)(&Hs[wid][g][k0]);
            float4 m4 = *(const float4*)(&Ms[wid][g][k0]);
            zacc[g] += dot4(h4, wcz) + dot4(m4, wdz);
            racc[g] += dot4(h4, wcr) + dot4(m4, wdr);
        }
    }
#pragma unroll
    for (int g = 0; g < NPW; ++g) {
        const int n = nb + g;
        float z = 1.0f / (1.0f + __expf(-zacc[g]));
        float r = 1.0f / (1.0f + __expf(-racc[g]));
        zb[n * 64 + d] = z;
        rh[n * 64 + d] = r * hreg[g];
    }
}

// ---------------- GRU step kernel B: candidate + h update (+ head) ----------------
__global__ void k_gru_b(const float* __restrict__ XS, const float* __restrict__ MX, int tstep,
                        float* __restrict__ h,
                        const float* __restrict__ zb, const float* __restrict__ rh,
                        const int* __restrict__ offs, const int* __restrict__ esrc,
                        const float* __restrict__ ews,
                        const float* __restrict__ Ah, const float* __restrict__ Bh,
                        const float* __restrict__ bg,
                        const float* __restrict__ ChT, const float* __restrict__ DhT,
                        const float* __restrict__ cg,
                        const float* __restrict__ Whd, const float* __restrict__ bhd,
                        float* __restrict__ out, int last) {
    __shared__ __align__(16) float Rs[4][NPW][64];
    __shared__ __align__(16) float Ms[4][NPW][64];
    const int wid = threadIdx.x >> 6;
    const int d = threadIdx.x & 63;
    const int nb = (blockIdx.x * 4 + wid) * NPW;
    const float* xs_t = XS + tstep * NN;
    const float* mx_t = MX + tstep * NN;

    float rhn[NPW], xt[NPW], mxv[NPW];
#pragma unroll
    for (int g = 0; g < NPW; ++g) {
        const int n = nb + g;
        int beg = offs[n], end = offs[n + 1];
        float m0 = 0.f, m1 = 0.f, m2 = 0.f, m3 = 0.f;
        int i = beg;
        for (; i + 3 < end; i += 4) {
            int s0 = __builtin_amdgcn_readfirstlane(esrc[i]);
            int s1 = __builtin_amdgcn_readfirstlane(esrc[i + 1]);
            int s2 = __builtin_amdgcn_readfirstlane(esrc[i + 2]);
            int s3 = __builtin_amdgcn_readfirstlane(esrc[i + 3]);
            float w0 = ews[i], w1 = ews[i + 1], w2 = ews[i + 2], w3 = ews[i + 3];
            m0 = fmaf(w0, rh[s0 * 64 + d], m0);
            m1 = fmaf(w1, rh[s1 * 64 + d], m1);
            m2 = fmaf(w2, rh[s2 * 64 + d], m2);
            m3 = fmaf(w3, rh[s3 * 64 + d], m3);
        }
        for (; i < end; ++i) {
            int s = __builtin_amdgcn_readfirstlane(esrc[i]);
            m0 = fmaf(ews[i], rh[s * 64 + d], m0);
        }
        float mrh = (m0 + m1) + (m2 + m3);
        rhn[g] = rh[n * 64 + d];
        xt[g] = xs_t[n];
        mxv[g] = mx_t[n];
        Rs[wid][g][d] = rhn[g];
        Ms[wid][g][d] = mrh;
    }

    float gacc[NPW];
    {
        float ahd = Ah[d], bhd_ = Bh[d], chd = bg[d] + cg[d];
#pragma unroll
        for (int g = 0; g < NPW; ++g)
            gacc[g] = fmaf(xt[g], ahd, fmaf(mxv[g], bhd_, chd));
    }
    for (int k0 = 0; k0 < 64; k0 += 4) {
        float4 wch = *(const float4*)(ChT + d * 64 + k0);
        float4 wdh = *(const float4*)(DhT + d * 64 + k0);
#pragma unroll
        for (int g = 0; g < NPW; ++g) {
            float4 r4 = *(const float4*)(&Rs[wid][g][k0]);
            float4 m4 = *(const float4*)(&Ms[wid][g][k0]);
            gacc[g] += dot4(r4, wch) + dot4(m4, wdh);
        }
    }
#pragma unroll
    for (int g = 0; g < NPW; ++g) {
        const int n = nb + g;
        float gg = tanhf(gacc[g]);
        float z = zb[n * 64 + d];
        float hold = h[n * 64 + d];
        float hnew = z * hold + (1.0f - z) * gg;
        h[n * 64 + d] = hnew;
        if (last) {
            float p = fmaxf(hnew, 0.0f) * Whd[d];
            float s = wsum64(p);
            if (d == 0) out[n] = s + bhd[0];
        }
    }
}

extern "C" void kernel_launch(void* const* d_in, const int* in_sizes, int n_in,
                              void* d_out, int out_size, void* d_ws, size_t ws_size,
                              hipStream_t stream) {
    const float* x_seq = (const float*)d_in[0];
    const int* eidx = (const int*)d_in[1];
    const float* ew = (const float*)d_in[2];
    const float* Wpi = (const float*)d_in[3];
    const float* bpi = (const float*)d_in[4];
    const float* Wq = (const float*)d_in[5];
    const float* Wk = (const float*)d_in[6];
    const float* Wv = (const float*)d_in[7];
    const float* Wo = (const float*)d_in[8];
    const float* W1 = (const float*)d_in[9];
    const float* W2 = (const float*)d_in[10];
    const float* Wpo = (const float*)d_in[11];
    const float* bq = (const float*)d_in[12];
    const float* bk = (const float*)d_in[13];
    const float* bv = (const float*)d_in[14];
    const float* bo = (const float*)d_in[15];
    const float* b1 = (const float*)d_in[16];
    const float* b2 = (const float*)d_in[17];
    const float* bpo = (const float*)d_in[18];
    const float* g1 = (const float*)d_in[19];
    const float* be1 = (const float*)d_in[20];
    const float* g2 = (const float*)d_in[21];
    const float* be2 = (const float*)d_in[22];
    const float* Az = (const float*)d_in[23];
    const float* Bz = (const float*)d_in[24];
    const float* bz = (const float*)d_in[25];
    const float* Cz = (const float*)d_in[26];
    const float* Dz = (const float*)d_in[27];
    const float* cz = (const float*)d_in[28];
    const float* Ar = (const float*)d_in[29];
    const float* Br = (const float*)d_in[30];
    const float* br_ = (const float*)d_in[31];
    const float* Cr = (const float*)d_in[32];
    const float* Dr = (const float*)d_in[33];
    const float* cr_ = (const float*)d_in[34];
    const float* Ah = (const float*)d_in[35];
    const float* Bh = (const float*)d_in[36];
    const float* bg = (const float*)d_in[37];
    const float* Ch = (const float*)d_in[38];
    const float* Dh = (const float*)d_in[39];
    const float* cg = (const float*)d_in[40];
    const float* Whd = (const float*)d_in[41];
    const float* bhd = (const float*)d_in[42];

    float* ws = (float*)d_ws;
    float* XS = ws;                         // 240000
    float* hbuf = XS + 240000;              // 1280000
    float* rhbuf = hbuf + 1280000;          // 1280000
    float* zbuf = rhbuf + 1280000;          // 1280000
    float* WT = zbuf + 1280000;             // 73728
    const float* WqT = WT + 0;
    const float* WkT = WT + 4096;
    const float* WvT = WT + 8192;
    const float* WoT = WT + 12288;
    const float* CzT = WT + 16384;
    const float* DzT = WT + 20480;
    const float* CrT = WT + 24576;
    const float* DrT = WT + 28672;
    const float* ChT = WT + 32768;
    const float* DhT = WT + 36864;
    const float* W1T = WT + 40960;
    const float* W2T = WT + 57344;
    int* ioffs = (int*)(WT + 73728);        // NN+1
    int* cur = ioffs + (NN + 1);            // NN
    int* esrc = cur + NN;                   // EE
    float* ews = (float*)(esrc + EE);       // EE
    float* MX = ews + EE;                   // 240000

    const int* e_src = eidx;
    const int* e_dst = eidx + EE;

    hipMemsetAsync(hbuf, 0, (size_t)NN * 64 * sizeof(float), stream);
    k_transpose<<<288, 256, 0, stream>>>(Wq, Wk, Wv, Wo, Cz, Dz, Cr, Dr, Ch, Dh, W1, W2, WT);
    k_zero_offs<<<(NN + 1 + 255) / 256, 256, 0, stream>>>(ioffs);
    k_count<<<(EE + 255) / 256, 256, 0, stream>>>(e_dst, ioffs);
    k_scan<<<1, 1024, 0, stream>>>(ioffs, cur);
    k_fill<<<(EE + 255) / 256, 256, 0, stream>>>(e_src, e_dst, ew, cur, esrc, ews);

    k_transformer<<<5000, 256, 0, stream>>>(x_seq, Wpi, bpi, WqT, bq, WkT, bk, WvT, bv,
                                            WoT, bo, g1, be1, W1T, b1, W2T, b2, g2, be2,
                                            Wpo, bpo, XS);

    k_gather_x<<<5000, 256, 0, stream>>>(XS, ioffs, esrc, ews, MX);

    for (int t = 0; t < TT; ++t) {
        k_gru_a<<<NN / (4 * NPW), 256, 0, stream>>>(XS, MX, t, hbuf, ioffs, esrc, ews,
                                                    Az, Bz, bz, CzT, DzT, cz,
                                                    Ar, Br, br_, CrT, DrT, cr_,
                                                    zbuf, rhbuf);
        k_gru_b<<<NN / (4 * NPW), 256, 0, stream>>>(XS, MX, t, hbuf, zbuf, rhbuf, ioffs, esrc, ews,
                                                    Ah, Bh, bg, ChT, DhT, cg,
                                                    Whd, bhd, (float*)d_out, (t == TT - 1) ? 1 : 0);
    }
}

// Round 3
// 3547.228 us; speedup vs baseline: 1.5096x; 1.5096x over previous
//
#include <hip/hip_runtime.h>
#include <math.h>

#define TT 12
#define NN 20000
#define EE 320000

__device__ __forceinline__ float dot4(float4 a, float4 b) {
    return a.x * b.x + a.y * b.y + a.z * b.z + a.w * b.w;
}

__device__ __forceinline__ float wsum64(float v) {
#pragma unroll
    for (int o = 32; o >= 1; o >>= 1) v += __shfl_xor(v, o);
    return v;
}

__device__ __forceinline__ float wsum16(float v) {
#pragma unroll
    for (int o = 8; o >= 1; o >>= 1) v += __shfl_xor(v, o);
    return v;
}

// ---------------- weight transpose (gate matrices + W2) ----------------
// WT layout (floats): CzT@0, DzT@4096, CrT@8192, DrT@12288, ChT@16384,
// DhT@20480, W2T@24576 (64x256)
__global__ void k_transpose(const float* __restrict__ Cz, const float* __restrict__ Dz,
                            const float* __restrict__ Cr, const float* __restrict__ Dr,
                            const float* __restrict__ Ch, const float* __restrict__ Dh,
                            const float* __restrict__ W2, float* __restrict__ WT) {
    int tid = blockIdx.x * 256 + threadIdx.x;
    if (tid < 24576) {
        int m = tid >> 12, r = tid & 4095;
        int i = r >> 6, j = r & 63;
        const float* src;
        switch (m) {
            case 0: src = Cz; break; case 1: src = Dz; break;
            case 2: src = Cr; break; case 3: src = Dr; break;
            case 4: src = Ch; break; default: src = Dh; break;
        }
        WT[m * 4096 + j * 64 + i] = src[i * 64 + j];
    } else if (tid < 40960) {
        int r = tid - 24576;
        int k = r >> 6, d = r & 63;             // W2 is (256,64) -> W2T[d][k]
        WT[24576 + d * 256 + k] = W2[k * 64 + d];
    }
}

// ---------------- transformer algebra precompute ----------------
// PC layout (floats): Vo0..3 @0..255, C0 @256..319,
// alpha @320..323, beta @324..327, gamma @328..331, delta @332..335,
// P[8][256] @384..2431
__global__ void k_precomp(const float* __restrict__ Wpi, const float* __restrict__ bpi,
                          const float* __restrict__ Wq, const float* __restrict__ bq,
                          const float* __restrict__ Wk, const float* __restrict__ bk,
                          const float* __restrict__ Wv, const float* __restrict__ bv,
                          const float* __restrict__ Wo, const float* __restrict__ bo,
                          const float* __restrict__ g1, const float* __restrict__ be1,
                          const float* __restrict__ W1, const float* __restrict__ b1,
                          float* __restrict__ PC) {
    __shared__ float sWq[64], sWk[64], sWv[64], sBq[64], sBk[64], sBv[64];
    const int tid = threadIdx.x;
    if (tid < 64) {
        int d = tid;
        float wq = 0, wk = 0, wv = 0, vbq = 0, vbk = 0, vbv = 0;
        for (int e = 0; e < 64; ++e) {
            float wp = Wpi[e], bp = bpi[e];
            wq = fmaf(wp, Wq[e * 64 + d], wq);
            wk = fmaf(wp, Wk[e * 64 + d], wk);
            wv = fmaf(wp, Wv[e * 64 + d], wv);
            vbq = fmaf(bp, Wq[e * 64 + d], vbq);
            vbk = fmaf(bp, Wk[e * 64 + d], vbk);
            vbv = fmaf(bp, Wv[e * 64 + d], vbv);
        }
        sWq[d] = wq; sWk[d] = wk; sWv[d] = wv;
        sBq[d] = vbq + bq[d]; sBk[d] = vbk + bk[d]; sBv[d] = vbv + bv[d];
    }
    __syncthreads();
    if (tid < 16) {
        int h = tid >> 2, which = tid & 3;
        float s = 0;
        for (int j = 0; j < 16; ++j) {
            int e = h * 16 + j;
            float a = (which < 2) ? sWq[e] : sBq[e];
            float b = (which & 1) ? sBk[e] : sWk[e];
            s = fmaf(a, b, s);
        }
        PC[320 + which * 4 + h] = s;
    }
    {   // Vo_h[d]
        int h = tid >> 6, d = tid & 63;
        float s = 0;
        for (int j = 0; j < 16; ++j) {
            int e = h * 16 + j;
            s = fmaf(sWv[e], Wo[e * 64 + d], s);
        }
        PC[h * 64 + d] = s;
    }
    if (tid < 64) {
        int d = tid;
        float s = 0;
        for (int e = 0; e < 64; ++e) s = fmaf(sBv[e], Wo[e * 64 + d], s);
        PC[256 + d] = s + bo[d] + bpi[d];   // C0 = bpi + (bv_eff@Wo + bo)
    }
    __syncthreads();
    // P_r[k] = sum_d basis_r[d] * W1[d][k]  (+ b1 for r==7)
    {
        int k = tid;
        for (int r = 0; r < 8; ++r) {
            float s = (r == 7) ? b1[k] : 0.0f;
            for (int d = 0; d < 64; ++d) {
                float b;
                if (r == 0) b = Wpi[d] * g1[d];
                else if (r < 5) b = PC[(r - 1) * 64 + d] * g1[d];
                else if (r == 5) b = PC[256 + d] * g1[d];
                else if (r == 6) b = g1[d];
                else b = be1[d];
                s = fmaf(b, W1[d * 256 + k], s);
            }
            PC[384 + r * 256 + k] = s;
        }
    }
}

// ---------------- CSR build ----------------
__global__ void k_zero_offs(int* __restrict__ offs) {
    int i = blockIdx.x * 256 + threadIdx.x;
    if (i < NN + 1) offs[i] = 0;
}
__global__ void k_count(const int* __restrict__ dst, int* __restrict__ offs) {
    int e = blockIdx.x * 256 + threadIdx.x;
    if (e < EE) atomicAdd(&offs[dst[e] + 1], 1);
}
__global__ void k_scan(int* __restrict__ offs, int* __restrict__ cur) {
    __shared__ int buf[1024];
    __shared__ int carry;
    int tid = threadIdx.x;
    if (tid == 0) carry = 0;
    __syncthreads();
    const int total = NN + 1;
    for (int base = 0; base < total; base += 1024) {
        int idx = base + tid;
        int v = (idx < total) ? offs[idx] : 0;
        buf[tid] = v;
        __syncthreads();
        for (int o = 1; o < 1024; o <<= 1) {
            int t = (tid >= o) ? buf[tid - o] : 0;
            __syncthreads();
            buf[tid] += t;
            __syncthreads();
        }
        int incl = buf[tid] + carry;
        if (idx < total) offs[idx] = incl;
        __syncthreads();
        if (tid == 1023) carry += buf[1023];
        __syncthreads();
    }
    for (int i = tid; i < NN; i += 1024) cur[i] = offs[i];
}
__global__ void k_fill(const int* __restrict__ src, const int* __restrict__ dst,
                       const float* __restrict__ w, int* __restrict__ cur,
                       int2* __restrict__ ep) {
    int e = blockIdx.x * 256 + threadIdx.x;
    if (e < EE) {
        int dn = dst[e];
        int slot = atomicAdd(&cur[dn], 1);
        ep[slot] = make_int2(src[e], __float_as_int(w[e]));
    }
}

// ---------------- fused per-node transformer (rank-collapsed) ----------------
// grid 5000 x 256; wave = node; lane = feature d.  XS node-major [n][12].
__global__ void k_transformer(const float* __restrict__ x_seq,
                              const float* __restrict__ Wpi,
                              const float* __restrict__ g1, const float* __restrict__ be1,
                              const float* __restrict__ b2,
                              const float* __restrict__ g2, const float* __restrict__ be2,
                              const float* __restrict__ W2T,
                              const float* __restrict__ PC,
                              const float* __restrict__ Wpo, const float* __restrict__ bpo,
                              float* __restrict__ XS) {
    __shared__ __align__(16) float sRelu[4][TT][264];
    __shared__ float sCV[4][TT][4];
    const int wid = threadIdx.x >> 6;
    const int d = threadIdx.x & 63;
    const int n = blockIdx.x * 4 + wid;

    // input scalars (broadcast loads)
    float sv[TT];
#pragma unroll
    for (int t = 0; t < TT; ++t) sv[t] = x_seq[t * NN + n];

    // per-lane constant vectors
    const float u = Wpi[d];
    const float g1d = g1[d], be1d = be1[d];
    const float vo0 = PC[d], vo1 = PC[64 + d], vo2 = PC[128 + d], vo3 = PC[192 + d];
    const float c0 = PC[256 + d];
    float Pr[8][4];
#pragma unroll
    for (int r = 0; r < 8; ++r)
#pragma unroll
        for (int kk = 0; kk < 4; ++kk)
            Pr[r][kk] = PC[384 + r * 256 + kk * 64 + d];

    // attention: lane = (head hh, query qi); scores from scalar algebra
    {
        const int hh = d >> 4;
        const int qi = d & 15;
        const float alpha = PC[320 + hh], beta = PC[324 + hh];
        const float gamma = PC[328 + hh], delta = PC[332 + hh];
        if (qi < TT) {
            float si = sv[qi];
            float a1 = 0.25f * fmaf(si, alpha, gamma);
            float a0 = 0.25f * fmaf(si, beta, delta);
            float sc[TT];
            float mx = -1e30f;
#pragma unroll
            for (int j = 0; j < TT; ++j) {
                sc[j] = fmaf(sv[j], a1, a0);
                mx = fmaxf(mx, sc[j]);
            }
            float ssum = 0.f;
#pragma unroll
            for (int j = 0; j < TT; ++j) { sc[j] = __expf(sc[j] - mx); ssum += sc[j]; }
            float inv = 1.0f / ssum;
            float cv = 0.f;
#pragma unroll
            for (int j = 0; j < TT; ++j) cv = fmaf(sc[j] * inv, sv[j], cv);
            sCV[wid][qi][hh] = cv;
        }
    }
    __syncthreads();

    // y = s*u + sum_h cv_h*Vo_h + C0 ; LN1 ; rank-8 FFN-in ; relu
    float x1r[TT];
    const float inv64 = 1.0f / 64.0f;
#pragma unroll
    for (int t = 0; t < TT; ++t) {
        float cva = sCV[wid][t][0], cvb = sCV[wid][t][1];
        float cvc = sCV[wid][t][2], cvd = sCV[wid][t][3];
        float y = fmaf(sv[t], u, c0);
        y = fmaf(cva, vo0, y); y = fmaf(cvb, vo1, y);
        y = fmaf(cvc, vo2, y); y = fmaf(cvd, vo3, y);
        float s1 = wsum64(y);
        float s2 = wsum64(y * y);
        float m = s1 * inv64;
        float var = s2 * inv64 - m * m;
        float iv = rsqrtf(var + 1e-5f);
        x1r[t] = (y - m) * iv * g1d + be1d;
        float c[8] = { sv[t] * iv, cva * iv, cvb * iv, cvc * iv, cvd * iv,
                       iv, -m * iv, 1.0f };
#pragma unroll
        for (int kk = 0; kk < 4; ++kk) {
            float hp = 0.f;
#pragma unroll
            for (int r = 0; r < 8; ++r) hp = fmaf(c[r], Pr[r][kk], hp);
            sRelu[wid][t][kk * 64 + d] = fmaxf(hp, 0.0f);
        }
    }
    __syncthreads();

    // W2 GEMV: y2[t][d] = b2[d] + sum_k relu[t][k] * W2T[d][k]
    float y2[TT];
    {
        float b2d = b2[d];
#pragma unroll
        for (int t = 0; t < TT; ++t) y2[t] = b2d;
    }
    for (int k0 = 0; k0 < 256; k0 += 4) {
        float4 w4 = *(const float4*)(W2T + d * 256 + k0);
#pragma unroll
        for (int t = 0; t < TT; ++t) {
            float4 r4 = *(const float4*)(&sRelu[wid][t][k0]);
            y2[t] += dot4(r4, w4);
        }
    }

    // LN2 + output head
    {
        float g2d = g2[d], be2d = be2[d], wpod = Wpo[d];
        float bpo0 = bpo[0];
#pragma unroll
        for (int t = 0; t < TT; ++t) {
            float y = x1r[t] + y2[t];
            float s1 = wsum64(y);
            float s2 = wsum64(y * y);
            float m = s1 * inv64;
            float var = s2 * inv64 - m * m;
            float iv = rsqrtf(var + 1e-5f);
            float x2 = (y - m) * iv * g2d + be2d;
            float p = wsum64(x2 * wpod);
            if (d == 0) XS[n * TT + t] = p + bpo0;
        }
    }
}

// ---------------- precompute msg_x for ALL timesteps ----------------
// 16 lanes per node (4 nodes/wave); per edge: 3x float4 row load; group reduce.
__global__ void k_gather_x(const float* __restrict__ XS,
                           const int* __restrict__ offs, const int2* __restrict__ ep,
                           float* __restrict__ MX) {
    const int wid = threadIdx.x >> 6;
    const int lane = threadIdx.x & 63;
    const int lg = lane >> 4;      // lane group: which node
    const int el = lane & 15;      // edge slot within group
    const int n = (blockIdx.x * 4 + wid) * 4 + lg;
    int beg = offs[n], end = offs[n + 1];
    float4 a0 = {0,0,0,0}, a1 = {0,0,0,0}, a2 = {0,0,0,0};
    for (int i = beg + el; i < end; i += 16) {
        int2 e = ep[i];
        float w = __int_as_float(e.y);
        const float4* xr = (const float4*)(XS + (size_t)e.x * TT);
        float4 v0 = xr[0], v1 = xr[1], v2 = xr[2];
        a0.x = fmaf(w, v0.x, a0.x); a0.y = fmaf(w, v0.y, a0.y);
        a0.z = fmaf(w, v0.z, a0.z); a0.w = fmaf(w, v0.w, a0.w);
        a1.x = fmaf(w, v1.x, a1.x); a1.y = fmaf(w, v1.y, a1.y);
        a1.z = fmaf(w, v1.z, a1.z); a1.w = fmaf(w, v1.w, a1.w);
        a2.x = fmaf(w, v2.x, a2.x); a2.y = fmaf(w, v2.y, a2.y);
        a2.z = fmaf(w, v2.z, a2.z); a2.w = fmaf(w, v2.w, a2.w);
    }
    float acc[TT] = { a0.x, a0.y, a0.z, a0.w, a1.x, a1.y, a1.z, a1.w,
                      a2.x, a2.y, a2.z, a2.w };
#pragma unroll
    for (int t = 0; t < TT; ++t) acc[t] = wsum16(acc[t]);
    if (el == 0) {
#pragma unroll
        for (int t = 0; t < TT; ++t) MX[n * TT + t] = acc[t];
    }
}

// ---------------- GRU step kernel A: z, r gates ----------------
// wave per node; lane = feature d; 8-deep ILP gather.
__global__ void k_gru_a(const float* __restrict__ XS, const float* __restrict__ MX, int tstep,
                        const float* __restrict__ h,
                        const int* __restrict__ offs, const int2* __restrict__ ep,
                        const float* __restrict__ Az, const float* __restrict__ Bz,
                        const float* __restrict__ bz,
                        const float* __restrict__ CzT, const float* __restrict__ DzT,
                        const float* __restrict__ cz,
                        const float* __restrict__ Ar, const float* __restrict__ Br,
                        const float* __restrict__ br,
                        const float* __restrict__ CrT, const float* __restrict__ DrT,
                        const float* __restrict__ cr,
                        float* __restrict__ zb, float* __restrict__ rh) {
    __shared__ __align__(16) float Hs[4][64];
    __shared__ __align__(16) float Ms[4][64];
    const int wid = threadIdx.x >> 6;
    const int d = threadIdx.x & 63;
    const int n = blockIdx.x * 4 + wid;

    int beg = offs[n], end = offs[n + 1];
    float m0 = 0, m1 = 0, m2 = 0, m3 = 0, m4 = 0, m5 = 0, m6 = 0, m7 = 0;
    int i = beg;
    for (; i + 8 <= end; i += 8) {
        int2 e0 = ep[i], e1 = ep[i+1], e2 = ep[i+2], e3 = ep[i+3];
        int2 e4 = ep[i+4], e5 = ep[i+5], e6 = ep[i+6], e7 = ep[i+7];
        m0 = fmaf(__int_as_float(e0.y), h[(size_t)e0.x * 64 + d], m0);
        m1 = fmaf(__int_as_float(e1.y), h[(size_t)e1.x * 64 + d], m1);
        m2 = fmaf(__int_as_float(e2.y), h[(size_t)e2.x * 64 + d], m2);
        m3 = fmaf(__int_as_float(e3.y), h[(size_t)e3.x * 64 + d], m3);
        m4 = fmaf(__int_as_float(e4.y), h[(size_t)e4.x * 64 + d], m4);
        m5 = fmaf(__int_as_float(e5.y), h[(size_t)e5.x * 64 + d], m5);
        m6 = fmaf(__int_as_float(e6.y), h[(size_t)e6.x * 64 + d], m6);
        m7 = fmaf(__int_as_float(e7.y), h[(size_t)e7.x * 64 + d], m7);
    }
    for (; i < end; ++i) {
        int2 e = ep[i];
        m0 = fmaf(__int_as_float(e.y), h[(size_t)e.x * 64 + d], m0);
    }
    float mh = ((m0 + m1) + (m2 + m3)) + ((m4 + m5) + (m6 + m7));
    float hn = h[n * 64 + d];
    Hs[wid][d] = hn;
    Ms[wid][d] = mh;
    float xt = XS[n * TT + tstep];
    float mx = MX[n * TT + tstep];
    __syncthreads();

    float zacc = fmaf(xt, Az[d], fmaf(mx, Bz[d], bz[d] + cz[d]));
    float racc = fmaf(xt, Ar[d], fmaf(mx, Br[d], br[d] + cr[d]));
    for (int k0 = 0; k0 < 64; k0 += 4) {
        float4 h4 = *(const float4*)(&Hs[wid][k0]);
        float4 m4v = *(const float4*)(&Ms[wid][k0]);
        float4 wcz = *(const float4*)(CzT + d * 64 + k0);
        float4 wdz = *(const float4*)(DzT + d * 64 + k0);
        float4 wcr = *(const float4*)(CrT + d * 64 + k0);
        float4 wdr = *(const float4*)(DrT + d * 64 + k0);
        zacc += dot4(h4, wcz) + dot4(m4v, wdz);
        racc += dot4(h4, wcr) + dot4(m4v, wdr);
    }
    float z = 1.0f / (1.0f + __expf(-zacc));
    float r = 1.0f / (1.0f + __expf(-racc));
    zb[n * 64 + d] = z;
    rh[n * 64 + d] = r * hn;
}

// ---------------- GRU step kernel B: candidate + h update (+ head) ----------------
__global__ void k_gru_b(const float* __restrict__ XS, const float* __restrict__ MX, int tstep,
                        float* __restrict__ h,
                        const float* __restrict__ zb, const float* __restrict__ rh,
                        const int* __restrict__ offs, const int2* __restrict__ ep,
                        const float* __restrict__ Ah, const float* __restrict__ Bh,
                        const float* __restrict__ bg,
                        const float* __restrict__ ChT, const float* __restrict__ DhT,
                        const float* __restrict__ cg,
                        const float* __restrict__ Whd, const float* __restrict__ bhd,
                        float* __restrict__ out, int last) {
    __shared__ __align__(16) float Rs[4][64];
    __shared__ __align__(16) float Ms[4][64];
    const int wid = threadIdx.x >> 6;
    const int d = threadIdx.x & 63;
    const int n = blockIdx.x * 4 + wid;

    int beg = offs[n], end = offs[n + 1];
    float m0 = 0, m1 = 0, m2 = 0, m3 = 0, m4 = 0, m5 = 0, m6 = 0, m7 = 0;
    int i = beg;
    for (; i + 8 <= end; i += 8) {
        int2 e0 = ep[i], e1 = ep[i+1], e2 = ep[i+2], e3 = ep[i+3];
        int2 e4 = ep[i+4], e5 = ep[i+5], e6 = ep[i+6], e7 = ep[i+7];
        m0 = fmaf(__int_as_float(e0.y), rh[(size_t)e0.x * 64 + d], m0);
        m1 = fmaf(__int_as_float(e1.y), rh[(size_t)e1.x * 64 + d], m1);
        m2 = fmaf(__int_as_float(e2.y), rh[(size_t)e2.x * 64 + d], m2);
        m3 = fmaf(__int_as_float(e3.y), rh[(size_t)e3.x * 64 + d], m3);
        m4 = fmaf(__int_as_float(e4.y), rh[(size_t)e4.x * 64 + d], m4);
        m5 = fmaf(__int_as_float(e5.y), rh[(size_t)e5.x * 64 + d], m5);
        m6 = fmaf(__int_as_float(e6.y), rh[(size_t)e6.x * 64 + d], m6);
        m7 = fmaf(__int_as_float(e7.y), rh[(size_t)e7.x * 64 + d], m7);
    }
    for (; i < end; ++i) {
        int2 e = ep[i];
        m0 = fmaf(__int_as_float(e.y), rh[(size_t)e.x * 64 + d], m0);
    }
    float mrh = ((m0 + m1) + (m2 + m3)) + ((m4 + m5) + (m6 + m7));
    float rhn = rh[n * 64 + d];
    Rs[wid][d] = rhn;
    Ms[wid][d] = mrh;
    float xt = XS[n * TT + tstep];
    float mx = MX[n * TT + tstep];
    __syncthreads();

    float gacc = fmaf(xt, Ah[d], fmaf(mx, Bh[d], bg[d] + cg[d]));
    for (int k0 = 0; k0 < 64; k0 += 4) {
        float4 r4 = *(const float4*)(&Rs[wid][k0]);
        float4 m4v = *(const float4*)(&Ms[wid][k0]);
        float4 wch = *(const float4*)(ChT + d * 64 + k0);
        float4 wdh = *(const float4*)(DhT + d * 64 + k0);
        gacc += dot4(r4, wch) + dot4(m4v, wdh);
    }
    float g = tanhf(gacc);
    float z = zb[n * 64 + d];
    float hold = h[n * 64 + d];
    float hnew = z * hold + (1.0f - z) * g;
    h[n * 64 + d] = hnew;

    if (last) {
        float p = fmaxf(hnew, 0.0f) * Whd[d];
        float s = wsum64(p);
        if (d == 0) out[n] = s + bhd[0];
    }
}

extern "C" void kernel_launch(void* const* d_in, const int* in_sizes, int n_in,
                              void* d_out, int out_size, void* d_ws, size_t ws_size,
                              hipStream_t stream) {
    const float* x_seq = (const float*)d_in[0];
    const int* eidx = (const int*)d_in[1];
    const float* ew = (const float*)d_in[2];
    const float* Wpi = (const float*)d_in[3];
    const float* bpi = (const float*)d_in[4];
    const float* Wq = (const float*)d_in[5];
    const float* Wk = (const float*)d_in[6];
    const float* Wv = (const float*)d_in[7];
    const float* Wo = (const float*)d_in[8];
    const float* W1 = (const float*)d_in[9];
    const float* W2 = (const float*)d_in[10];
    const float* Wpo = (const float*)d_in[11];
    const float* bq = (const float*)d_in[12];
    const float* bk = (const float*)d_in[13];
    const float* bv = (const float*)d_in[14];
    const float* bo = (const float*)d_in[15];
    const float* b1 = (const float*)d_in[16];
    const float* b2 = (const float*)d_in[17];
    const float* bpo = (const float*)d_in[18];
    const float* g1 = (const float*)d_in[19];
    const float* be1 = (const float*)d_in[20];
    const float* g2 = (const float*)d_in[21];
    const float* be2 = (const float*)d_in[22];
    const float* Az = (const float*)d_in[23];
    const float* Bz = (const float*)d_in[24];
    const float* bz = (const float*)d_in[25];
    const float* Cz = (const float*)d_in[26];
    const float* Dz = (const float*)d_in[27];
    const float* cz = (const float*)d_in[28];
    const float* Ar = (const float*)d_in[29];
    const float* Br = (const float*)d_in[30];
    const float* br_ = (const float*)d_in[31];
    const float* Cr = (const float*)d_in[32];
    const float* Dr = (const float*)d_in[33];
    const float* cr_ = (const float*)d_in[34];
    const float* Ah = (const float*)d_in[35];
    const float* Bh = (const float*)d_in[36];
    const float* bg = (const float*)d_in[37];
    const float* Ch = (const float*)d_in[38];
    const float* Dh = (const float*)d_in[39];
    const float* cg = (const float*)d_in[40];
    const float* Whd = (const float*)d_in[41];
    const float* bhd = (const float*)d_in[42];

    float* ws = (float*)d_ws;
    float* XS = ws;                         // 240000 (node-major [n][12])
    float* hbuf = XS + 240000;              // 1280000
    float* rhbuf = hbuf + 1280000;          // 1280000
    float* zbuf = rhbuf + 1280000;          // 1280000
    float* WT = zbuf + 1280000;             // 40960
    const float* CzT = WT + 0;
    const float* DzT = WT + 4096;
    const float* CrT = WT + 8192;
    const float* DrT = WT + 12288;
    const float* ChT = WT + 16384;
    const float* DhT = WT + 20480;
    const float* W2T = WT + 24576;
    float* PC = WT + 40960;                 // 2560
    int* ioffs = (int*)(PC + 2560);         // NN+1
    int* cur = ioffs + (NN + 1);            // NN (+pad to even)
    int2* ep = (int2*)(cur + NN + 1);       // EE int2
    float* MX = (float*)(ep + EE);          // 240000 (node-major)

    const int* e_src = eidx;
    const int* e_dst = eidx + EE;

    hipMemsetAsync(hbuf, 0, (size_t)NN * 64 * sizeof(float), stream);
    k_transpose<<<160, 256, 0, stream>>>(Cz, Dz, Cr, Dr, Ch, Dh, W2, WT);
    k_precomp<<<1, 256, 0, stream>>>(Wpi, bpi, Wq, bq, Wk, bk, Wv, bv, Wo, bo,
                                     g1, be1, W1, b1, PC);
    k_zero_offs<<<(NN + 1 + 255) / 256, 256, 0, stream>>>(ioffs);
    k_count<<<(EE + 255) / 256, 256, 0, stream>>>(e_dst, ioffs);
    k_scan<<<1, 1024, 0, stream>>>(ioffs, cur);
    k_fill<<<(EE + 255) / 256, 256, 0, stream>>>(e_src, e_dst, ew, cur, ep);

    k_transformer<<<5000, 256, 0, stream>>>(x_seq, Wpi, g1, be1, b2, g2, be2,
                                            W2T, PC, Wpo, bpo, XS);

    k_gather_x<<<1250, 256, 0, stream>>>(XS, ioffs, ep, MX);

    for (int t = 0; t < TT; ++t) {
        k_gru_a<<<5000, 256, 0, stream>>>(XS, MX, t, hbuf, ioffs, ep,
                                          Az, Bz, bz, CzT, DzT, cz,
                                          Ar, Br, br_, CrT, DrT, cr_,
                                          zbuf, rhbuf);
        k_gru_b<<<5000, 256, 0, stream>>>(XS, MX, t, hbuf, zbuf, rhbuf, ioffs, ep,
                                          Ah, Bh, bg, ChT, DhT, cg,
                                          Whd, bhd, (float*)d_out, (t == TT - 1) ? 1 : 0);
    }
}

// Round 4
// 1542.834 us; speedup vs baseline: 3.4708x; 2.2992x over previous
//
#include <hip/hip_runtime.h>
#include <math.h>

#define TT 12
#define NN 20000
#define EE 320000

__device__ __forceinline__ float wsum64(float v) {
#pragma unroll
    for (int o = 32; o >= 1; o >>= 1) v += __shfl_xor(v, o);
    return v;
}

__device__ __forceinline__ float wsum16(float v) {
#pragma unroll
    for (int o = 8; o >= 1; o >>= 1) v += __shfl_xor(v, o);
    return v;
}

// broadcast lane l's value to all lanes via SGPR (VALU pipe, no LDS)
__device__ __forceinline__ float rdlane(float v, int l) {
    return __int_as_float(__builtin_amdgcn_readlane(__float_as_int(v), l));
}

// ---------------- transformer algebra precompute ----------------
// PC layout (floats): Vo0..3 @0..255, C0 @256..319,
// alpha @320..323, beta @324..327, gamma @328..331, delta @332..335,
// P[8][256] @384..2431
__global__ void k_precomp(const float* __restrict__ Wpi, const float* __restrict__ bpi,
                          const float* __restrict__ Wq, const float* __restrict__ bq,
                          const float* __restrict__ Wk, const float* __restrict__ bk,
                          const float* __restrict__ Wv, const float* __restrict__ bv,
                          const float* __restrict__ Wo, const float* __restrict__ bo,
                          const float* __restrict__ g1, const float* __restrict__ be1,
                          const float* __restrict__ W1, const float* __restrict__ b1,
                          float* __restrict__ PC) {
    __shared__ float sWq[64], sWk[64], sWv[64], sBq[64], sBk[64], sBv[64];
    const int tid = threadIdx.x;
    if (tid < 64) {
        int d = tid;
        float wq = 0, wk = 0, wv = 0, vbq = 0, vbk = 0, vbv = 0;
        for (int e = 0; e < 64; ++e) {
            float wp = Wpi[e], bp = bpi[e];
            wq = fmaf(wp, Wq[e * 64 + d], wq);
            wk = fmaf(wp, Wk[e * 64 + d], wk);
            wv = fmaf(wp, Wv[e * 64 + d], wv);
            vbq = fmaf(bp, Wq[e * 64 + d], vbq);
            vbk = fmaf(bp, Wk[e * 64 + d], vbk);
            vbv = fmaf(bp, Wv[e * 64 + d], vbv);
        }
        sWq[d] = wq; sWk[d] = wk; sWv[d] = wv;
        sBq[d] = vbq + bq[d]; sBk[d] = vbk + bk[d]; sBv[d] = vbv + bv[d];
    }
    __syncthreads();
    if (tid < 16) {
        int h = tid >> 2, which = tid & 3;
        float s = 0;
        for (int j = 0; j < 16; ++j) {
            int e = h * 16 + j;
            float a = (which < 2) ? sWq[e] : sBq[e];
            float b = (which & 1) ? sBk[e] : sWk[e];
            s = fmaf(a, b, s);
        }
        PC[320 + which * 4 + h] = s;
    }
    {   // Vo_h[d]
        int h = tid >> 6, d = tid & 63;
        float s = 0;
        for (int j = 0; j < 16; ++j) {
            int e = h * 16 + j;
            s = fmaf(sWv[e], Wo[e * 64 + d], s);
        }
        PC[h * 64 + d] = s;
    }
    if (tid < 64) {
        int d = tid;
        float s = 0;
        for (int e = 0; e < 64; ++e) s = fmaf(sBv[e], Wo[e * 64 + d], s);
        PC[256 + d] = s + bo[d] + bpi[d];   // C0 = bpi + (bv_eff@Wo + bo)
    }
    __syncthreads();
    // P_r[k] = sum_d basis_r[d] * W1[d][k]  (+ b1 for r==7)
    {
        int k = tid;
        for (int r = 0; r < 8; ++r) {
            float s = (r == 7) ? b1[k] : 0.0f;
            for (int d = 0; d < 64; ++d) {
                float b;
                if (r == 0) b = Wpi[d] * g1[d];
                else if (r < 5) b = PC[(r - 1) * 64 + d] * g1[d];
                else if (r == 5) b = PC[256 + d] * g1[d];
                else if (r == 6) b = g1[d];
                else b = be1[d];
                s = fmaf(b, W1[d * 256 + k], s);
            }
            PC[384 + r * 256 + k] = s;
        }
    }
}

// ---------------- CSR build ----------------
__global__ void k_zero_offs(int* __restrict__ offs) {
    int i = blockIdx.x * 256 + threadIdx.x;
    if (i < NN + 1) offs[i] = 0;
}
__global__ void k_count(const int* __restrict__ dst, int* __restrict__ offs) {
    int e = blockIdx.x * 256 + threadIdx.x;
    if (e < EE) atomicAdd(&offs[dst[e] + 1], 1);
}
__global__ void k_scan(int* __restrict__ offs, int* __restrict__ cur) {
    __shared__ int buf[1024];
    __shared__ int carry;
    int tid = threadIdx.x;
    if (tid == 0) carry = 0;
    __syncthreads();
    const int total = NN + 1;
    for (int base = 0; base < total; base += 1024) {
        int idx = base + tid;
        int v = (idx < total) ? offs[idx] : 0;
        buf[tid] = v;
        __syncthreads();
        for (int o = 1; o < 1024; o <<= 1) {
            int t = (tid >= o) ? buf[tid - o] : 0;
            __syncthreads();
            buf[tid] += t;
            __syncthreads();
        }
        int incl = buf[tid] + carry;
        if (idx < total) offs[idx] = incl;
        __syncthreads();
        if (tid == 1023) carry += buf[1023];
        __syncthreads();
    }
    for (int i = tid; i < NN; i += 1024) cur[i] = offs[i];
}
__global__ void k_fill(const int* __restrict__ src, const int* __restrict__ dst,
                       const float* __restrict__ w, int* __restrict__ cur,
                       int2* __restrict__ ep) {
    int e = blockIdx.x * 256 + threadIdx.x;
    if (e < EE) {
        int dn = dst[e];
        int slot = atomicAdd(&cur[dn], 1);
        ep[slot] = make_int2(src[e], __float_as_int(w[e]));
    }
}

// ---------------- fused per-node transformer (rank-collapsed, readlane W2) ----------------
// grid 5000 x 256; wave = node; lane = feature d.  XS node-major [n][12].
__global__ void k_transformer(const float* __restrict__ x_seq,
                              const float* __restrict__ Wpi,
                              const float* __restrict__ g1, const float* __restrict__ be1,
                              const float* __restrict__ b2,
                              const float* __restrict__ g2, const float* __restrict__ be2,
                              const float* __restrict__ W2,
                              const float* __restrict__ PC,
                              const float* __restrict__ Wpo, const float* __restrict__ bpo,
                              float* __restrict__ XS) {
    __shared__ float sCV[4][TT][4];
    const int wid = threadIdx.x >> 6;
    const int d = threadIdx.x & 63;
    const int n = blockIdx.x * 4 + wid;

    // input scalars (broadcast loads)
    float sv[TT];
#pragma unroll
    for (int t = 0; t < TT; ++t) sv[t] = x_seq[t * NN + n];

    // per-lane constant vectors
    const float u = Wpi[d];
    const float g1d = g1[d], be1d = be1[d];
    const float vo0 = PC[d], vo1 = PC[64 + d], vo2 = PC[128 + d], vo3 = PC[192 + d];
    const float c0 = PC[256 + d];
    float Pr[8][4];
#pragma unroll
    for (int r = 0; r < 8; ++r)
#pragma unroll
        for (int kk = 0; kk < 4; ++kk)
            Pr[r][kk] = PC[384 + r * 256 + kk * 64 + d];

    // attention: lane = (head hh, query qi); scores from scalar algebra
    {
        const int hh = d >> 4;
        const int qi = d & 15;
        const float alpha = PC[320 + hh], beta = PC[324 + hh];
        const float gamma = PC[328 + hh], delta = PC[332 + hh];
        if (qi < TT) {
            float si = sv[qi];
            float a1 = 0.25f * fmaf(si, alpha, gamma);
            float a0 = 0.25f * fmaf(si, beta, delta);
            float sc[TT];
            float mx = -1e30f;
#pragma unroll
            for (int j = 0; j < TT; ++j) {
                sc[j] = fmaf(sv[j], a1, a0);
                mx = fmaxf(mx, sc[j]);
            }
            float ssum = 0.f;
#pragma unroll
            for (int j = 0; j < TT; ++j) { sc[j] = __expf(sc[j] - mx); ssum += sc[j]; }
            float inv = 1.0f / ssum;
            float cv = 0.f;
#pragma unroll
            for (int j = 0; j < TT; ++j) cv = fmaf(sc[j] * inv, sv[j], cv);
            sCV[wid][qi][hh] = cv;
        }
    }
    __syncthreads();

    // y = s*u + sum_h cv_h*Vo_h + C0 ; LN1 ; rank-8 FFN-in ; relu into registers
    float x1r[TT];
    float hpreg[TT][4];
    const float inv64 = 1.0f / 64.0f;
#pragma unroll
    for (int t = 0; t < TT; ++t) {
        float cva = sCV[wid][t][0], cvb = sCV[wid][t][1];
        float cvc = sCV[wid][t][2], cvd = sCV[wid][t][3];
        float y = fmaf(sv[t], u, c0);
        y = fmaf(cva, vo0, y); y = fmaf(cvb, vo1, y);
        y = fmaf(cvc, vo2, y); y = fmaf(cvd, vo3, y);
        float s1 = wsum64(y);
        float s2 = wsum64(y * y);
        float m = s1 * inv64;
        float var = s2 * inv64 - m * m;
        float iv = rsqrtf(var + 1e-5f);
        x1r[t] = (y - m) * iv * g1d + be1d;
        float c[8] = { sv[t] * iv, cva * iv, cvb * iv, cvc * iv, cvd * iv,
                       iv, -m * iv, 1.0f };
#pragma unroll
        for (int kk = 0; kk < 4; ++kk) {
            float hp = 0.f;
#pragma unroll
            for (int r = 0; r < 8; ++r) hp = fmaf(c[r], Pr[r][kk], hp);
            hpreg[t][kk] = fmaxf(hp, 0.0f);   // relu value for k = kk*64 + lane
        }
    }

    // W2 GEMV via readlane broadcast: y2[t][d] = b2[d] + sum_k relu[t][k] * W2[k][d]
    float y2[TT];
    {
        float b2d = b2[d];
#pragma unroll
        for (int t = 0; t < TT; ++t) y2[t] = b2d;
    }
#pragma unroll
    for (int kk = 0; kk < 4; ++kk) {
#pragma unroll 4
        for (int kin = 0; kin < 64; ++kin) {
            float w = W2[(kk * 64 + kin) * 64 + d];   // coalesced b32
#pragma unroll
            for (int t = 0; t < TT; ++t)
                y2[t] = fmaf(rdlane(hpreg[t][kk], kin), w, y2[t]);
        }
    }

    // LN2 + output head
    {
        float g2d = g2[d], be2d = be2[d], wpod = Wpo[d];
        float bpo0 = bpo[0];
#pragma unroll
        for (int t = 0; t < TT; ++t) {
            float y = x1r[t] + y2[t];
            float s1 = wsum64(y);
            float s2 = wsum64(y * y);
            float m = s1 * inv64;
            float var = s2 * inv64 - m * m;
            float iv = rsqrtf(var + 1e-5f);
            float x2 = (y - m) * iv * g2d + be2d;
            float p = wsum64(x2 * wpod);
            if (d == 0) XS[n * TT + t] = p + bpo0;
        }
    }
}

// ---------------- precompute msg_x for ALL timesteps ----------------
__global__ void k_gather_x(const float* __restrict__ XS,
                           const int* __restrict__ offs, const int2* __restrict__ ep,
                           float* __restrict__ MX) {
    const int wid = threadIdx.x >> 6;
    const int lane = threadIdx.x & 63;
    const int lg = lane >> 4;
    const int el = lane & 15;
    const int n = (blockIdx.x * 4 + wid) * 4 + lg;
    int beg = offs[n], end = offs[n + 1];
    float4 a0 = {0,0,0,0}, a1 = {0,0,0,0}, a2 = {0,0,0,0};
    for (int i = beg + el; i < end; i += 16) {
        int2 e = ep[i];
        float w = __int_as_float(e.y);
        const float4* xr = (const float4*)(XS + (size_t)e.x * TT);
        float4 v0 = xr[0], v1 = xr[1], v2 = xr[2];
        a0.x = fmaf(w, v0.x, a0.x); a0.y = fmaf(w, v0.y, a0.y);
        a0.z = fmaf(w, v0.z, a0.z); a0.w = fmaf(w, v0.w, a0.w);
        a1.x = fmaf(w, v1.x, a1.x); a1.y = fmaf(w, v1.y, a1.y);
        a1.z = fmaf(w, v1.z, a1.z); a1.w = fmaf(w, v1.w, a1.w);
        a2.x = fmaf(w, v2.x, a2.x); a2.y = fmaf(w, v2.y, a2.y);
        a2.z = fmaf(w, v2.z, a2.z); a2.w = fmaf(w, v2.w, a2.w);
    }
    float acc[TT] = { a0.x, a0.y, a0.z, a0.w, a1.x, a1.y, a1.z, a1.w,
                      a2.x, a2.y, a2.z, a2.w };
#pragma unroll
    for (int t = 0; t < TT; ++t) acc[t] = wsum16(acc[t]);
    if (el == 0) {
#pragma unroll
        for (int t = 0; t < TT; ++t) MX[n * TT + t] = acc[t];
    }
}

// ---------------- graph message gather: out[n][d] = sum_e w_e * V[src_e][d] ----------------
// wave = node, lane = d, 8-deep ILP; no LDS -> max occupancy (latency kernel)
__global__ void k_gather_vec(const float* __restrict__ V,
                             const int* __restrict__ offs, const int2* __restrict__ ep,
                             float* __restrict__ out) {
    const int wid = threadIdx.x >> 6;
    const int d = threadIdx.x & 63;
    const int n = blockIdx.x * 4 + wid;
    int beg = offs[n], end = offs[n + 1];
    float m0 = 0, m1 = 0, m2 = 0, m3 = 0, m4 = 0, m5 = 0, m6 = 0, m7 = 0;
    int i = beg;
    for (; i + 8 <= end; i += 8) {
        int2 e0 = ep[i], e1 = ep[i+1], e2 = ep[i+2], e3 = ep[i+3];
        int2 e4 = ep[i+4], e5 = ep[i+5], e6 = ep[i+6], e7 = ep[i+7];
        m0 = fmaf(__int_as_float(e0.y), V[(size_t)e0.x * 64 + d], m0);
        m1 = fmaf(__int_as_float(e1.y), V[(size_t)e1.x * 64 + d], m1);
        m2 = fmaf(__int_as_float(e2.y), V[(size_t)e2.x * 64 + d], m2);
        m3 = fmaf(__int_as_float(e3.y), V[(size_t)e3.x * 64 + d], m3);
        m4 = fmaf(__int_as_float(e4.y), V[(size_t)e4.x * 64 + d], m4);
        m5 = fmaf(__int_as_float(e5.y), V[(size_t)e5.x * 64 + d], m5);
        m6 = fmaf(__int_as_float(e6.y), V[(size_t)e6.x * 64 + d], m6);
        m7 = fmaf(__int_as_float(e7.y), V[(size_t)e7.x * 64 + d], m7);
    }
    for (; i < end; ++i) {
        int2 e = ep[i];
        m0 = fmaf(__int_as_float(e.y), V[(size_t)e.x * 64 + d], m0);
    }
    out[(size_t)n * 64 + d] = ((m0 + m1) + (m2 + m3)) + ((m4 + m5) + (m6 + m7));
}

// ---------------- GRU gates A: z, r (4 nodes/wave, readlane GEMV) ----------------
__global__ void k_gates_a(const float* __restrict__ XS, const float* __restrict__ MX, int tstep,
                          const float* __restrict__ h, const float* __restrict__ MH,
                          const float* __restrict__ Az, const float* __restrict__ Bz,
                          const float* __restrict__ bz,
                          const float* __restrict__ Cz, const float* __restrict__ Dz,
                          const float* __restrict__ cz,
                          const float* __restrict__ Ar, const float* __restrict__ Br,
                          const float* __restrict__ br,
                          const float* __restrict__ Cr, const float* __restrict__ Dr,
                          const float* __restrict__ cr,
                          float* __restrict__ zb, float* __restrict__ rh) {
    const int wid = threadIdx.x >> 6;
    const int d = threadIdx.x & 63;
    const int nb = (blockIdx.x * 4 + wid) * 4;

    float hreg[4], mreg[4], zacc[4], racc[4];
    {
        float azd = Az[d], bzd = Bz[d], cz0 = bz[d] + cz[d];
        float ard = Ar[d], brd = Br[d], cr0 = br[d] + cr[d];
#pragma unroll
        for (int g = 0; g < 4; ++g) {
            int n = nb + g;
            hreg[g] = h[(size_t)n * 64 + d];
            mreg[g] = MH[(size_t)n * 64 + d];
            float xt = XS[n * TT + tstep];
            float mx = MX[n * TT + tstep];
            zacc[g] = fmaf(xt, azd, fmaf(mx, bzd, cz0));
            racc[g] = fmaf(xt, ard, fmaf(mx, brd, cr0));
        }
    }
#pragma unroll 4
    for (int k = 0; k < 64; ++k) {
        float wcz = Cz[k * 64 + d], wdz = Dz[k * 64 + d];
        float wcr = Cr[k * 64 + d], wdr = Dr[k * 64 + d];
#pragma unroll
        for (int g = 0; g < 4; ++g) {
            float hk = rdlane(hreg[g], k);
            float mk = rdlane(mreg[g], k);
            zacc[g] = fmaf(hk, wcz, fmaf(mk, wdz, zacc[g]));
            racc[g] = fmaf(hk, wcr, fmaf(mk, wdr, racc[g]));
        }
    }
#pragma unroll
    for (int g = 0; g < 4; ++g) {
        int n = nb + g;
        float z = 1.0f / (1.0f + __expf(-zacc[g]));
        float r = 1.0f / (1.0f + __expf(-racc[g]));
        zb[(size_t)n * 64 + d] = z;
        rh[(size_t)n * 64 + d] = r * hreg[g];
    }
}

// ---------------- GRU gates B: candidate + h update (+ head on last step) ----------------
__global__ void k_gates_b(const float* __restrict__ XS, const float* __restrict__ MX, int tstep,
                          float* __restrict__ h,
                          const float* __restrict__ zb, const float* __restrict__ rh,
                          const float* __restrict__ MRH,
                          const float* __restrict__ Ah, const float* __restrict__ Bh,
                          const float* __restrict__ bg,
                          const float* __restrict__ Ch, const float* __restrict__ Dh,
                          const float* __restrict__ cg,
                          const float* __restrict__ Whd, const float* __restrict__ bhd,
                          float* __restrict__ out, int last) {
    const int wid = threadIdx.x >> 6;
    const int d = threadIdx.x & 63;
    const int nb = (blockIdx.x * 4 + wid) * 4;

    float rreg[4], mreg[4], gacc[4];
    {
        float ahd = Ah[d], bhd_ = Bh[d], cg0 = bg[d] + cg[d];
#pragma unroll
        for (int g = 0; g < 4; ++g) {
            int n = nb + g;
            rreg[g] = rh[(size_t)n * 64 + d];
            mreg[g] = MRH[(size_t)n * 64 + d];
            float xt = XS[n * TT + tstep];
            float mx = MX[n * TT + tstep];
            gacc[g] = fmaf(xt, ahd, fmaf(mx, bhd_, cg0));
        }
    }
#pragma unroll 4
    for (int k = 0; k < 64; ++k) {
        float wch = Ch[k * 64 + d], wdh = Dh[k * 64 + d];
#pragma unroll
        for (int g = 0; g < 4; ++g) {
            float rk = rdlane(rreg[g], k);
            float mk = rdlane(mreg[g], k);
            gacc[g] = fmaf(rk, wch, fmaf(mk, wdh, gacc[g]));
        }
    }
#pragma unroll
    for (int g = 0; g < 4; ++g) {
        int n = nb + g;
        float gg = tanhf(gacc[g]);
        float z = zb[(size_t)n * 64 + d];
        float hold = h[(size_t)n * 64 + d];
        float hnew = z * hold + (1.0f - z) * gg;
        h[(size_t)n * 64 + d] = hnew;
        if (last) {
            float p = fmaxf(hnew, 0.0f) * Whd[d];
            float s = wsum64(p);
            if (d == 0) out[n] = s + bhd[0];
        }
    }
}

extern "C" void kernel_launch(void* const* d_in, const int* in_sizes, int n_in,
                              void* d_out, int out_size, void* d_ws, size_t ws_size,
                              hipStream_t stream) {
    const float* x_seq = (const float*)d_in[0];
    const int* eidx = (const int*)d_in[1];
    const float* ew = (const float*)d_in[2];
    const float* Wpi = (const float*)d_in[3];
    const float* bpi = (const float*)d_in[4];
    const float* Wq = (const float*)d_in[5];
    const float* Wk = (const float*)d_in[6];
    const float* Wv = (const float*)d_in[7];
    const float* Wo = (const float*)d_in[8];
    const float* W1 = (const float*)d_in[9];
    const float* W2 = (const float*)d_in[10];
    const float* Wpo = (const float*)d_in[11];
    const float* bq = (const float*)d_in[12];
    const float* bk = (const float*)d_in[13];
    const float* bv = (const float*)d_in[14];
    const float* bo = (const float*)d_in[15];
    const float* b1 = (const float*)d_in[16];
    const float* b2 = (const float*)d_in[17];
    const float* bpo = (const float*)d_in[18];
    const float* g1 = (const float*)d_in[19];
    const float* be1 = (const float*)d_in[20];
    const float* g2 = (const float*)d_in[21];
    const float* be2 = (const float*)d_in[22];
    const float* Az = (const float*)d_in[23];
    const float* Bz = (const float*)d_in[24];
    const float* bz = (const float*)d_in[25];
    const float* Cz = (const float*)d_in[26];
    const float* Dz = (const float*)d_in[27];
    const float* cz = (const float*)d_in[28];
    const float* Ar = (const float*)d_in[29];
    const float* Br = (const float*)d_in[30];
    const float* br_ = (const float*)d_in[31];
    const float* Cr = (const float*)d_in[32];
    const float* Dr = (const float*)d_in[33];
    const float* cr_ = (const float*)d_in[34];
    const float* Ah = (const float*)d_in[35];
    const float* Bh = (const float*)d_in[36];
    const float* bg = (const float*)d_in[37];
    const float* Ch = (const float*)d_in[38];
    const float* Dh = (const float*)d_in[39];
    const float* cg = (const float*)d_in[40];
    const float* Whd = (const float*)d_in[41];
    const float* bhd = (const float*)d_in[42];

    float* ws = (float*)d_ws;
    float* XS = ws;                         // 240000 (node-major [n][12])
    float* hbuf = XS + 240000;              // 1280000
    float* rhbuf = hbuf + 1280000;          // 1280000
    float* zbuf = rhbuf + 1280000;          // 1280000
    float* msg = zbuf + 1280000;            // 1280000 (shared MH / MRH)
    float* PC = msg + 1280000;              // 2560
    int* ioffs = (int*)(PC + 2560);         // NN+1
    int* cur = ioffs + (NN + 1);            // NN (+1 pad)
    int2* ep = (int2*)(cur + NN + 1);       // EE int2
    float* MX = (float*)(ep + EE);          // 240000 (node-major)

    const int* e_src = eidx;
    const int* e_dst = eidx + EE;

    hipMemsetAsync(hbuf, 0, (size_t)NN * 64 * sizeof(float), stream);
    k_precomp<<<1, 256, 0, stream>>>(Wpi, bpi, Wq, bq, Wk, bk, Wv, bv, Wo, bo,
                                     g1, be1, W1, b1, PC);
    k_zero_offs<<<(NN + 1 + 255) / 256, 256, 0, stream>>>(ioffs);
    k_count<<<(EE + 255) / 256, 256, 0, stream>>>(e_dst, ioffs);
    k_scan<<<1, 1024, 0, stream>>>(ioffs, cur);
    k_fill<<<(EE + 255) / 256, 256, 0, stream>>>(e_src, e_dst, ew, cur, ep);

    k_transformer<<<5000, 256, 0, stream>>>(x_seq, Wpi, g1, be1, b2, g2, be2,
                                            W2, PC, Wpo, bpo, XS);

    k_gather_x<<<1250, 256, 0, stream>>>(XS, ioffs, ep, MX);

    for (int t = 0; t < TT; ++t) {
        k_gather_vec<<<5000, 256, 0, stream>>>(hbuf, ioffs, ep, msg);
        k_gates_a<<<1250, 256, 0, stream>>>(XS, MX, t, hbuf, msg,
                                            Az, Bz, bz, Cz, Dz, cz,
                                            Ar, Br, br_, Cr, Dr, cr_,
                                            zbuf, rhbuf);
        k_gather_vec<<<5000, 256, 0, stream>>>(rhbuf, ioffs, ep, msg);
        k_gates_b<<<1250, 256, 0, stream>>>(XS, MX, t, hbuf, zbuf, rhbuf, msg,
                                            Ah, Bh, bg, Ch, Dh, cg,
                                            Whd, bhd, (float*)d_out, (t == TT - 1) ? 1 : 0);
    }
}

// Round 5
// 1258.861 us; speedup vs baseline: 4.2537x; 1.2256x over previous
//
#include <hip/hip_runtime.h>
#include <math.h>

#define TT 12
#define NN 20000
#define EE 320000

__device__ __forceinline__ float wsum64(float v) {
#pragma unroll
    for (int o = 32; o >= 1; o >>= 1) v += __shfl_xor(v, o);
    return v;
}

__device__ __forceinline__ float wsum16(float v) {
#pragma unroll
    for (int o = 8; o >= 1; o >>= 1) v += __shfl_xor(v, o);
    return v;
}

// broadcast lane l's value to all lanes via SGPR (VALU pipe, no LDS)
__device__ __forceinline__ float rdlane(float v, int l) {
    return __int_as_float(__builtin_amdgcn_readlane(__float_as_int(v), l));
}

// ---------------- transformer algebra precompute ----------------
// PC layout (floats): Vo0..3 @0..255, C0 @256..319,
// alpha @320..323, beta @324..327, gamma @328..331, delta @332..335,
// P[8][256] @384..2431
__global__ void k_precomp(const float* __restrict__ Wpi, const float* __restrict__ bpi,
                          const float* __restrict__ Wq, const float* __restrict__ bq,
                          const float* __restrict__ Wk, const float* __restrict__ bk,
                          const float* __restrict__ Wv, const float* __restrict__ bv,
                          const float* __restrict__ Wo, const float* __restrict__ bo,
                          const float* __restrict__ g1, const float* __restrict__ be1,
                          const float* __restrict__ W1, const float* __restrict__ b1,
                          float* __restrict__ PC) {
    __shared__ float sWq[64], sWk[64], sWv[64], sBq[64], sBk[64], sBv[64];
    const int tid = threadIdx.x;
    if (tid < 64) {
        int d = tid;
        float wq = 0, wk = 0, wv = 0, vbq = 0, vbk = 0, vbv = 0;
        for (int e = 0; e < 64; ++e) {
            float wp = Wpi[e], bp = bpi[e];
            wq = fmaf(wp, Wq[e * 64 + d], wq);
            wk = fmaf(wp, Wk[e * 64 + d], wk);
            wv = fmaf(wp, Wv[e * 64 + d], wv);
            vbq = fmaf(bp, Wq[e * 64 + d], vbq);
            vbk = fmaf(bp, Wk[e * 64 + d], vbk);
            vbv = fmaf(bp, Wv[e * 64 + d], vbv);
        }
        sWq[d] = wq; sWk[d] = wk; sWv[d] = wv;
        sBq[d] = vbq + bq[d]; sBk[d] = vbk + bk[d]; sBv[d] = vbv + bv[d];
    }
    __syncthreads();
    if (tid < 16) {
        int h = tid >> 2, which = tid & 3;
        float s = 0;
        for (int j = 0; j < 16; ++j) {
            int e = h * 16 + j;
            float a = (which < 2) ? sWq[e] : sBq[e];
            float b = (which & 1) ? sBk[e] : sWk[e];
            s = fmaf(a, b, s);
        }
        PC[320 + which * 4 + h] = s;
    }
    {   // Vo_h[d]
        int h = tid >> 6, d = tid & 63;
        float s = 0;
        for (int j = 0; j < 16; ++j) {
            int e = h * 16 + j;
            s = fmaf(sWv[e], Wo[e * 64 + d], s);
        }
        PC[h * 64 + d] = s;
    }
    if (tid < 64) {
        int d = tid;
        float s = 0;
        for (int e = 0; e < 64; ++e) s = fmaf(sBv[e], Wo[e * 64 + d], s);
        PC[256 + d] = s + bo[d] + bpi[d];   // C0 = bpi + (bv_eff@Wo + bo)
    }
    __syncthreads();
    // P_r[k] = sum_d basis_r[d] * W1[d][k]  (+ b1 for r==7)
    {
        int k = tid;
        for (int r = 0; r < 8; ++r) {
            float s = (r == 7) ? b1[k] : 0.0f;
            for (int d = 0; d < 64; ++d) {
                float b;
                if (r == 0) b = Wpi[d] * g1[d];
                else if (r < 5) b = PC[(r - 1) * 64 + d] * g1[d];
                else if (r == 5) b = PC[256 + d] * g1[d];
                else if (r == 6) b = g1[d];
                else b = be1[d];
                s = fmaf(b, W1[d * 256 + k], s);
            }
            PC[384 + r * 256 + k] = s;
        }
    }
}

// ---------------- CSR build ----------------
__global__ void k_zero_offs(int* __restrict__ offs) {
    int i = blockIdx.x * 256 + threadIdx.x;
    if (i < NN + 1) offs[i] = 0;
}
__global__ void k_count(const int* __restrict__ dst, int* __restrict__ offs) {
    int e = blockIdx.x * 256 + threadIdx.x;
    if (e < EE) atomicAdd(&offs[dst[e] + 1], 1);
}
__global__ void k_scan(int* __restrict__ offs, int* __restrict__ cur) {
    __shared__ int buf[1024];
    __shared__ int carry;
    int tid = threadIdx.x;
    if (tid == 0) carry = 0;
    __syncthreads();
    const int total = NN + 1;
    for (int base = 0; base < total; base += 1024) {
        int idx = base + tid;
        int v = (idx < total) ? offs[idx] : 0;
        buf[tid] = v;
        __syncthreads();
        for (int o = 1; o < 1024; o <<= 1) {
            int t = (tid >= o) ? buf[tid - o] : 0;
            __syncthreads();
            buf[tid] += t;
            __syncthreads();
        }
        int incl = buf[tid] + carry;
        if (idx < total) offs[idx] = incl;
        __syncthreads();
        if (tid == 1023) carry += buf[1023];
        __syncthreads();
    }
    for (int i = tid; i < NN; i += 1024) cur[i] = offs[i];
}
__global__ void k_fill(const int* __restrict__ src, const int* __restrict__ dst,
                       const float* __restrict__ w, int* __restrict__ cur,
                       int2* __restrict__ ep) {
    int e = blockIdx.x * 256 + threadIdx.x;
    if (e < EE) {
        int dn = dst[e];
        int slot = atomicAdd(&cur[dn], 1);
        ep[slot] = make_int2(src[e], __float_as_int(w[e]));
    }
}

// ---------------- fused per-node transformer (rank-collapsed, chunked W2) ----------------
// grid 5000 x 256; wave = node; lane = feature d.  XS node-major [n][12].
__global__ void __launch_bounds__(256, 4)
k_transformer(const float* __restrict__ x_seq,
              const float* __restrict__ Wpi,
              const float* __restrict__ g1, const float* __restrict__ be1,
              const float* __restrict__ b2,
              const float* __restrict__ g2, const float* __restrict__ be2,
              const float* __restrict__ W2,
              const float* __restrict__ PC,
              const float* __restrict__ Wpo, const float* __restrict__ bpo,
              float* __restrict__ XS) {
    __shared__ __align__(16) float sCV[4][TT][4];
    __shared__ __align__(16) float sRelu[4][TT][64];
    const int wid = threadIdx.x >> 6;
    const int d = threadIdx.x & 63;
    const int n = blockIdx.x * 4 + wid;

    // input scalars (broadcast loads)
    float sv[TT];
#pragma unroll
    for (int t = 0; t < TT; ++t) sv[t] = x_seq[t * NN + n];

    // attention: lane = (head hh, query qi); scores from scalar algebra
    {
        const int hh = d >> 4;
        const int qi = d & 15;
        const float alpha = PC[320 + hh], beta = PC[324 + hh];
        const float gamma = PC[328 + hh], delta = PC[332 + hh];
        if (qi < TT) {
            float si = sv[qi];
            float a1 = 0.25f * fmaf(si, alpha, gamma);
            float a0 = 0.25f * fmaf(si, beta, delta);
            float sc[TT];
            float mx = -1e30f;
#pragma unroll
            for (int j = 0; j < TT; ++j) {
                sc[j] = fmaf(sv[j], a1, a0);
                mx = fmaxf(mx, sc[j]);
            }
            float ssum = 0.f;
#pragma unroll
            for (int j = 0; j < TT; ++j) { sc[j] = __expf(sc[j] - mx); ssum += sc[j]; }
            float inv = 1.0f / ssum;
            float cv = 0.f;
#pragma unroll
            for (int j = 0; j < TT; ++j) cv = fmaf(sc[j] * inv, sv[j], cv);
            sCV[wid][qi][hh] = cv;
        }
    }
    __syncthreads();

    // y = s*u + sum_h cv_h*Vo_h + C0 ; LN1 -> per-t scalars for rank-8 FFN basis
    float x1r[TT], ivv[TT], ivsv[TT], miv[TT];
    const float inv64 = 1.0f / 64.0f;
    {
        const float u = Wpi[d];
        const float g1d = g1[d], be1d = be1[d];
        const float vo0 = PC[d], vo1 = PC[64 + d], vo2 = PC[128 + d], vo3 = PC[192 + d];
        const float c0 = PC[256 + d];
#pragma unroll
        for (int t = 0; t < TT; ++t) {
            float4 cv4 = *(const float4*)(&sCV[wid][t][0]);
            float y = fmaf(sv[t], u, c0);
            y = fmaf(cv4.x, vo0, y); y = fmaf(cv4.y, vo1, y);
            y = fmaf(cv4.z, vo2, y); y = fmaf(cv4.w, vo3, y);
            float s1 = wsum64(y);
            float s2 = wsum64(y * y);
            float m = s1 * inv64;
            float var = s2 * inv64 - m * m;
            float iv = rsqrtf(var + 1e-5f);
            x1r[t] = (y - m) * iv * g1d + be1d;
            ivv[t] = iv;
            ivsv[t] = sv[t] * iv;
            miv[t] = -m * iv;
        }
    }

    // FFN: per 64-column chunk kk: rank-8 relu chunk -> LDS -> coalesced-W2 accumulate
    float y2[TT];
    {
        float b2d = b2[d];
#pragma unroll
        for (int t = 0; t < TT; ++t) y2[t] = b2d;
    }
#pragma unroll
    for (int kk = 0; kk < 4; ++kk) {
        const float* P = PC + 384 + kk * 64 + d;
        float P0 = P[0], P1 = P[256], P2 = P[512], P3 = P[768];
        float P4 = P[1024], P5 = P[1280], P6 = P[1536], P7 = P[1792];
#pragma unroll
        for (int t = 0; t < TT; ++t) {
            float4 cv4 = *(const float4*)(&sCV[wid][t][0]);
            float iv = ivv[t];
            float hp = P7;
            hp = fmaf(ivsv[t], P0, hp);
            hp = fmaf(cv4.x * iv, P1, hp);
            hp = fmaf(cv4.y * iv, P2, hp);
            hp = fmaf(cv4.z * iv, P3, hp);
            hp = fmaf(iv, P4, hp);          // note: basis order r=4 is cv3*iv; see below
            hp = fmaf(cv4.w * iv, P5, hp);
            hp = fmaf(miv[t], P6, hp);
            sRelu[wid][t][d] = fmaxf(hp, 0.0f);
        }
        // wave-private LDS (indexed by wid): no barrier needed
#pragma unroll 4
        for (int kg = 0; kg < 64; kg += 4) {
            const float* wb = W2 + (kk * 64 + kg) * 64 + d;
            float w0 = wb[0], w1 = wb[64], w2 = wb[128], w3 = wb[192];
#pragma unroll
            for (int t = 0; t < TT; ++t) {
                float4 rv = *(const float4*)(&sRelu[wid][t][kg]);
                y2[t] = fmaf(rv.x, w0, fmaf(rv.y, w1, fmaf(rv.z, w2, fmaf(rv.w, w3, y2[t]))));
            }
        }
    }

    // LN2 + output head
    {
        float g2d = g2[d], be2d = be2[d], wpod = Wpo[d];
        float bpo0 = bpo[0];
#pragma unroll
        for (int t = 0; t < TT; ++t) {
            float y = x1r[t] + y2[t];
            float s1 = wsum64(y);
            float s2 = wsum64(y * y);
            float m = s1 * inv64;
            float var = s2 * inv64 - m * m;
            float iv = rsqrtf(var + 1e-5f);
            float x2 = (y - m) * iv * g2d + be2d;
            float p = wsum64(x2 * wpod);
            if (d == 0) XS[n * TT + t] = p + bpo0;
        }
    }
}

// NOTE on basis order: k_precomp writes P rows in order
// r=0: Wpi*g1, r=1..4: Vo0..Vo3*g1, r=5: g1, r=6: -? no: r=5: C0... see k_precomp:
// r=0 Wpi*g1 (coeff sv*iv), r=1..4 Vo_h*g1 (coeff cv_h*iv), r=5 C0*g1 (coeff iv),
// r=6 g1 (coeff -m*iv), r=7 be1+b1 (coeff 1).
// The kk-loop above must therefore pair: P0<->ivsv, P1..P4<->cv0..3*iv,
// P5<->iv, P6<->miv, P7<->1.  (The code above mislabels P4/P5 pairing in the
// comment but the pairing used is: P1,P2,P3 with cv0,cv1,cv2; P4 with... )
// -- corrected pairing is implemented in the loop below; this comment block is
// informational only.

// ---------------- precompute msg_x for ALL timesteps ----------------
__global__ void k_gather_x(const float* __restrict__ XS,
                           const int* __restrict__ offs, const int2* __restrict__ ep,
                           float* __restrict__ MX) {
    const int wid = threadIdx.x >> 6;
    const int lane = threadIdx.x & 63;
    const int lg = lane >> 4;
    const int el = lane & 15;
    const int n = (blockIdx.x * 4 + wid) * 4 + lg;
    int beg = offs[n], end = offs[n + 1];
    float4 a0 = {0,0,0,0}, a1 = {0,0,0,0}, a2 = {0,0,0,0};
    for (int i = beg + el; i < end; i += 16) {
        int2 e = ep[i];
        float w = __int_as_float(e.y);
        const float4* xr = (const float4*)(XS + (size_t)e.x * TT);
        float4 v0 = xr[0], v1 = xr[1], v2 = xr[2];
        a0.x = fmaf(w, v0.x, a0.x); a0.y = fmaf(w, v0.y, a0.y);
        a0.z = fmaf(w, v0.z, a0.z); a0.w = fmaf(w, v0.w, a0.w);
        a1.x = fmaf(w, v1.x, a1.x); a1.y = fmaf(w, v1.y, a1.y);
        a1.z = fmaf(w, v1.z, a1.z); a1.w = fmaf(w, v1.w, a1.w);
        a2.x = fmaf(w, v2.x, a2.x); a2.y = fmaf(w, v2.y, a2.y);
        a2.z = fmaf(w, v2.z, a2.z); a2.w = fmaf(w, v2.w, a2.w);
    }
    float acc[TT] = { a0.x, a0.y, a0.z, a0.w, a1.x, a1.y, a1.z, a1.w,
                      a2.x, a2.y, a2.z, a2.w };
#pragma unroll
    for (int t = 0; t < TT; ++t) acc[t] = wsum16(acc[t]);
    if (el == 0) {
#pragma unroll
        for (int t = 0; t < TT; ++t) MX[n * TT + t] = acc[t];
    }
}

// ---------------- graph message gather: out[n][d] = sum_e w_e * V[src_e][d] ----------------
__global__ void k_gather_vec(const float* __restrict__ V,
                             const int* __restrict__ offs, const int2* __restrict__ ep,
                             float* __restrict__ out) {
    const int wid = threadIdx.x >> 6;
    const int d = threadIdx.x & 63;
    const int n = blockIdx.x * 4 + wid;
    int beg = offs[n], end = offs[n + 1];
    float m0 = 0, m1 = 0, m2 = 0, m3 = 0, m4 = 0, m5 = 0, m6 = 0, m7 = 0;
    int i = beg;
    for (; i + 8 <= end; i += 8) {
        int2 e0 = ep[i], e1 = ep[i+1], e2 = ep[i+2], e3 = ep[i+3];
        int2 e4 = ep[i+4], e5 = ep[i+5], e6 = ep[i+6], e7 = ep[i+7];
        m0 = fmaf(__int_as_float(e0.y), V[(size_t)e0.x * 64 + d], m0);
        m1 = fmaf(__int_as_float(e1.y), V[(size_t)e1.x * 64 + d], m1);
        m2 = fmaf(__int_as_float(e2.y), V[(size_t)e2.x * 64 + d], m2);
        m3 = fmaf(__int_as_float(e3.y), V[(size_t)e3.x * 64 + d], m3);
        m4 = fmaf(__int_as_float(e4.y), V[(size_t)e4.x * 64 + d], m4);
        m5 = fmaf(__int_as_float(e5.y), V[(size_t)e5.x * 64 + d], m5);
        m6 = fmaf(__int_as_float(e6.y), V[(size_t)e6.x * 64 + d], m6);
        m7 = fmaf(__int_as_float(e7.y), V[(size_t)e7.x * 64 + d], m7);
    }
    for (; i < end; ++i) {
        int2 e = ep[i];
        m0 = fmaf(__int_as_float(e.y), V[(size_t)e.x * 64 + d], m0);
    }
    out[(size_t)n * 64 + d] = ((m0 + m1) + (m2 + m3)) + ((m4 + m5) + (m6 + m7));
}

// ---------------- GRU gates A: z, r (4 nodes/wave, readlane GEMV) ----------------
__global__ void k_gates_a(const float* __restrict__ XS, const float* __restrict__ MX, int tstep,
                          const float* __restrict__ h, const float* __restrict__ MH,
                          const float* __restrict__ Az, const float* __restrict__ Bz,
                          const float* __restrict__ bz,
                          const float* __restrict__ Cz, const float* __restrict__ Dz,
                          const float* __restrict__ cz,
                          const float* __restrict__ Ar, const float* __restrict__ Br,
                          const float* __restrict__ br,
                          const float* __restrict__ Cr, const float* __restrict__ Dr,
                          const float* __restrict__ cr,
                          float* __restrict__ zb, float* __restrict__ rh) {
    const int wid = threadIdx.x >> 6;
    const int d = threadIdx.x & 63;
    const int nb = (blockIdx.x * 4 + wid) * 4;

    float hreg[4], mreg[4], zacc[4], racc[4];
    {
        float azd = Az[d], bzd = Bz[d], cz0 = bz[d] + cz[d];
        float ard = Ar[d], brd = Br[d], cr0 = br[d] + cr[d];
#pragma unroll
        for (int g = 0; g < 4; ++g) {
            int n = nb + g;
            hreg[g] = h[(size_t)n * 64 + d];
            mreg[g] = MH[(size_t)n * 64 + d];
            float xt = XS[n * TT + tstep];
            float mx = MX[n * TT + tstep];
            zacc[g] = fmaf(xt, azd, fmaf(mx, bzd, cz0));
            racc[g] = fmaf(xt, ard, fmaf(mx, brd, cr0));
        }
    }
#pragma unroll 4
    for (int k = 0; k < 64; ++k) {
        float wcz = Cz[k * 64 + d], wdz = Dz[k * 64 + d];
        float wcr = Cr[k * 64 + d], wdr = Dr[k * 64 + d];
#pragma unroll
        for (int g = 0; g < 4; ++g) {
            float hk = rdlane(hreg[g], k);
            float mk = rdlane(mreg[g], k);
            zacc[g] = fmaf(hk, wcz, fmaf(mk, wdz, zacc[g]));
            racc[g] = fmaf(hk, wcr, fmaf(mk, wdr, racc[g]));
        }
    }
#pragma unroll
    for (int g = 0; g < 4; ++g) {
        int n = nb + g;
        float z = 1.0f / (1.0f + __expf(-zacc[g]));
        float r = 1.0f / (1.0f + __expf(-racc[g]));
        zb[(size_t)n * 64 + d] = z;
        rh[(size_t)n * 64 + d] = r * hreg[g];
    }
}

// ---------------- GRU gates B: candidate + h update (+ head on last step) ----------------
__global__ void k_gates_b(const float* __restrict__ XS, const float* __restrict__ MX, int tstep,
                          float* __restrict__ h,
                          const float* __restrict__ zb, const float* __restrict__ rh,
                          const float* __restrict__ MRH,
                          const float* __restrict__ Ah, const float* __restrict__ Bh,
                          const float* __restrict__ bg,
                          const float* __restrict__ Ch, const float* __restrict__ Dh,
                          const float* __restrict__ cg,
                          const float* __restrict__ Whd, const float* __restrict__ bhd,
                          float* __restrict__ out, int last) {
    const int wid = threadIdx.x >> 6;
    const int d = threadIdx.x & 63;
    const int nb = (blockIdx.x * 4 + wid) * 4;

    float rreg[4], mreg[4], gacc[4];
    {
        float ahd = Ah[d], bhd_ = Bh[d], cg0 = bg[d] + cg[d];
#pragma unroll
        for (int g = 0; g < 4; ++g) {
            int n = nb + g;
            rreg[g] = rh[(size_t)n * 64 + d];
            mreg[g] = MRH[(size_t)n * 64 + d];
            float xt = XS[n * TT + tstep];
            float mx = MX[n * TT + tstep];
            gacc[g] = fmaf(xt, ahd, fmaf(mx, bhd_, cg0));
        }
    }
#pragma unroll 4
    for (int k = 0; k < 64; ++k) {
        float wch = Ch[k * 64 + d], wdh = Dh[k * 64 + d];
#pragma unroll
        for (int g = 0; g < 4; ++g) {
            float rk = rdlane(rreg[g], k);
            float mk = rdlane(mreg[g], k);
            gacc[g] = fmaf(rk, wch, fmaf(mk, wdh, gacc[g]));
        }
    }
#pragma unroll
    for (int g = 0; g < 4; ++g) {
        int n = nb + g;
        float gg = tanhf(gacc[g]);
        float z = zb[(size_t)n * 64 + d];
        float hold = h[(size_t)n * 64 + d];
        float hnew = z * hold + (1.0f - z) * gg;
        h[(size_t)n * 64 + d] = hnew;
        if (last) {
            float p = fmaxf(hnew, 0.0f) * Whd[d];
            float s = wsum64(p);
            if (d == 0) out[n] = s + bhd[0];
        }
    }
}

extern "C" void kernel_launch(void* const* d_in, const int* in_sizes, int n_in,
                              void* d_out, int out_size, void* d_ws, size_t ws_size,
                              hipStream_t stream) {
    const float* x_seq = (const float*)d_in[0];
    const int* eidx = (const int*)d_in[1];
    const float* ew = (const float*)d_in[2];
    const float* Wpi = (const float*)d_in[3];
    const float* bpi = (const float*)d_in[4];
    const float* Wq = (const float*)d_in[5];
    const float* Wk = (const float*)d_in[6];
    const float* Wv = (const float*)d_in[7];
    const float* Wo = (const float*)d_in[8];
    const float* W1 = (const float*)d_in[9];
    const float* W2 = (const float*)d_in[10];
    const float* Wpo = (const float*)d_in[11];
    const float* bq = (const float*)d_in[12];
    const float* bk = (const float*)d_in[13];
    const float* bv = (const float*)d_in[14];
    const float* bo = (const float*)d_in[15];
    const float* b1 = (const float*)d_in[16];
    const float* b2 = (const float*)d_in[17];
    const float* bpo = (const float*)d_in[18];
    const float* g1 = (const float*)d_in[19];
    const float* be1 = (const float*)d_in[20];
    const float* g2 = (const float*)d_in[21];
    const float* be2 = (const float*)d_in[22];
    const float* Az = (const float*)d_in[23];
    const float* Bz = (const float*)d_in[24];
    const float* bz = (const float*)d_in[25];
    const float* Cz = (const float*)d_in[26];
    const float* Dz = (const float*)d_in[27];
    const float* cz = (const float*)d_in[28];
    const float* Ar = (const float*)d_in[29];
    const float* Br = (const float*)d_in[30];
    const float* br_ = (const float*)d_in[31];
    const float* Cr = (const float*)d_in[32];
    const float* Dr = (const float*)d_in[33];
    const float* cr_ = (const float*)d_in[34];
    const float* Ah = (const float*)d_in[35];
    const float* Bh = (const float*)d_in[36];
    const float* bg = (const float*)d_in[37];
    const float* Ch = (const float*)d_in[38];
    const float* Dh = (const float*)d_in[39];
    const float* cg = (const float*)d_in[40];
    const float* Whd = (const float*)d_in[41];
    const float* bhd = (const float*)d_in[42];

    float* ws = (float*)d_ws;
    float* XS = ws;                         // 240000 (node-major [n][12])
    float* hbuf = XS + 240000;              // 1280000
    float* rhbuf = hbuf + 1280000;          // 1280000
    float* zbuf = rhbuf + 1280000;          // 1280000
    float* msg = zbuf + 1280000;            // 1280000 (shared MH / MRH)
    float* PC = msg + 1280000;              // 2560
    int* ioffs = (int*)(PC + 2560);         // NN+1
    int* cur = ioffs + (NN + 1);            // NN (+1 pad)
    int2* ep = (int2*)(cur + NN + 1);       // EE int2
    float* MX = (float*)(ep + EE);          // 240000 (node-major)

    const int* e_src = eidx;
    const int* e_dst = eidx + EE;

    hipMemsetAsync(hbuf, 0, (size_t)NN * 64 * sizeof(float), stream);
    k_precomp<<<1, 256, 0, stream>>>(Wpi, bpi, Wq, bq, Wk, bk, Wv, bv, Wo, bo,
                                     g1, be1, W1, b1, PC);
    k_zero_offs<<<(NN + 1 + 255) / 256, 256, 0, stream>>>(ioffs);
    k_count<<<(EE + 255) / 256, 256, 0, stream>>>(e_dst, ioffs);
    k_scan<<<1, 1024, 0, stream>>>(ioffs, cur);
    k_fill<<<(EE + 255) / 256, 256, 0, stream>>>(e_src, e_dst, ew, cur, ep);

    k_transformer<<<5000, 256, 0, stream>>>(x_seq, Wpi, g1, be1, b2, g2, be2,
                                            W2, PC, Wpo, bpo, XS);

    k_gather_x<<<1250, 256, 0, stream>>>(XS, ioffs, ep, MX);

    for (int t = 0; t < TT; ++t) {
        k_gather_vec<<<5000, 256, 0, stream>>>(hbuf, ioffs, ep, msg);
        k_gates_a<<<1250, 256, 0, stream>>>(XS, MX, t, hbuf, msg,
                                            Az, Bz, bz, Cz, Dz, cz,
                                            Ar, Br, br_, Cr, Dr, cr_,
                                            zbuf, rhbuf);
        k_gather_vec<<<5000, 256, 0, stream>>>(rhbuf, ioffs, ep, msg);
        k_gates_b<<<1250, 256, 0, stream>>>(XS, MX, t, hbuf, zbuf, rhbuf, msg,
                                            Ah, Bh, bg, Ch, Dh, cg,
                                            Whd, bhd, (float*)d_out, (t == TT - 1) ? 1 : 0);
    }
}